// Round 1
// baseline (301.211 us; speedup 1.0000x reference)
//
#include <hip/hip_runtime.h>
#include <hip/hip_bf16.h>
#include <stdint.h>

#define BATCH 2
#define SEQ 2048
#define NHEADS 16
#define DH 64
#define DIM 1024
#define MTOT 4096            // BATCH*SEQ
#define LOG2E 1.4426950408889634f
#define QSCALE (0.125f * LOG2E)   // d^-0.5 * log2(e), folded into Q

typedef __attribute__((ext_vector_type(8))) short s16x8;   // 8 bf16
typedef __attribute__((ext_vector_type(4))) float f32x4;
typedef unsigned short u16;

__device__ __forceinline__ u16 f2b(float f) {
  union { float f; uint32_t u; } v; v.f = f;
  uint32_t r = v.u + 0x7FFFu + ((v.u >> 16) & 1u);
  return (u16)(r >> 16);
}
__device__ __forceinline__ float b2f(u16 h) {
  union { uint32_t u; float f; } v; v.u = ((uint32_t)h) << 16;
  return v.f;
}

// async global->LDS, 16B per lane. LDS dest must be uniform-base + lane*16.
__device__ __forceinline__ void gload_lds16(void* lds, const void* g) {
  __builtin_amdgcn_global_load_lds(
      (const __attribute__((address_space(1))) unsigned int*)g,
      (__attribute__((address_space(3))) unsigned int*)lds, 16, 0, 0);
}

// ---------------- prep kernels ----------------

__global__ __launch_bounds__(256) void cast_x_kernel(
    const float* __restrict__ x, u16* __restrict__ xb) {
  int i = (blockIdx.x * 256 + threadIdx.x) * 4;
  float4 v = *(const float4*)(x + i);
  ushort4 o;
  o.x = f2b(v.x); o.y = f2b(v.y); o.z = f2b(v.z); o.w = f2b(v.w);
  *(ushort4*)(xb + i) = o;
}

// W (K=1024 x N=1024) f32 -> Wt (N x K) bf16, z selects which weight
__global__ __launch_bounds__(256) void transw_kernel(
    const float* __restrict__ Wq, const float* __restrict__ Wk,
    const float* __restrict__ Wv, const float* __restrict__ Wo,
    u16* __restrict__ WtAll) {
  const float* W = (blockIdx.z == 0) ? Wq : (blockIdx.z == 1) ? Wk
                 : (blockIdx.z == 2) ? Wv : Wo;
  u16* Wt = WtAll + (size_t)blockIdx.z * DIM * DIM;
  __shared__ float t[32][33];
  int k0 = blockIdx.x * 32, n0 = blockIdx.y * 32;
  int tx = threadIdx.x, ty = threadIdx.y;   // (32,8)
#pragma unroll
  for (int i = 0; i < 4; i++) {
    int r = ty + i * 8;
    t[r][tx] = W[(size_t)(k0 + r) * DIM + n0 + tx];
  }
  __syncthreads();
#pragma unroll
  for (int i = 0; i < 4; i++) {
    int r = ty + i * 8;                      // output row = n
    Wt[(size_t)(n0 + r) * DIM + k0 + tx] = f2b(t[tx][r]);
  }
}

__global__ __launch_bounds__(256) void table_kernel(
    const float* __restrict__ rot, float2* __restrict__ cs) {
  int i = blockIdx.x * 256 + threadIdx.x;    // SEQ*32 = 65536
  float f = rot[i];
  float s, c;
  __sincosf(f, &s, &c);
  cs[i] = make_float2(c, s);
}

// ---------------- GEMM: C(M x N) = A(M x K) * Bt(N x K)^T ----------------
// 128x128 tile, BK=32, 4 waves each owning a 64x64 quadrant.
template <bool OBF16>
__global__ __launch_bounds__(256) void gemm128(
    const u16* __restrict__ A, const u16* __restrict__ BtBase,
    void* __restrict__ Cbase) {
  __shared__ u16 Asm[128][32];
  __shared__ u16 Bsm[128][32];
  const u16* Bt = BtBase + (size_t)blockIdx.z * DIM * DIM;

  int t = threadIdx.x;
  int w = t >> 6, l = t & 63;
  int wr = w >> 1, wc = w & 1;
  int lr = l & 15, lg = l >> 4;
  int rowBase = blockIdx.x * 128;
  int colBase = blockIdx.y * 128;

  const u16* Ab = A + (size_t)rowBase * DIM;
  const u16* Bb = Bt + (size_t)colBase * DIM;

  f32x4 acc[4][4];
#pragma unroll
  for (int m = 0; m < 4; m++)
#pragma unroll
    for (int n = 0; n < 4; n++) acc[m][n] = (f32x4){0.f, 0.f, 0.f, 0.f};

  for (int kt = 0; kt < DIM / 32; ++kt) {
#pragma unroll
    for (int i = 0; i < 2; i++) {
      int ob = t * 16 + i * 4096;            // byte offset in 8192B tile
      int row = ob >> 6;                     // 64 B per row (32 bf16)
      int cb = ob & 63;
      gload_lds16((char*)Asm + ob, (const char*)(Ab + (size_t)row * DIM + kt * 32) + cb);
      gload_lds16((char*)Bsm + ob, (const char*)(Bb + (size_t)row * DIM + kt * 32) + cb);
    }
    __syncthreads();
    s16x8 af[4], bf[4];
#pragma unroll
    for (int m = 0; m < 4; m++) af[m] = *(const s16x8*)&Asm[wr * 64 + m * 16 + lr][lg * 8];
#pragma unroll
    for (int n = 0; n < 4; n++) bf[n] = *(const s16x8*)&Bsm[wc * 64 + n * 16 + lr][lg * 8];
#pragma unroll
    for (int m = 0; m < 4; m++)
#pragma unroll
      for (int n = 0; n < 4; n++)
        acc[m][n] = __builtin_amdgcn_mfma_f32_16x16x32_bf16(af[m], bf[n], acc[m][n], 0, 0, 0);
    __syncthreads();
  }

  if constexpr (OBF16) {
    u16* C = (u16*)Cbase + (size_t)blockIdx.z * MTOT * DIM;
#pragma unroll
    for (int m = 0; m < 4; m++)
#pragma unroll
      for (int n = 0; n < 4; n++) {
        int row = rowBase + wr * 64 + m * 16 + lg * 4;
        int col = colBase + wc * 64 + n * 16 + lr;
#pragma unroll
        for (int r = 0; r < 4; r++)
          C[(size_t)(row + r) * DIM + col] = f2b(acc[m][n][r]);
      }
  } else {
    float* C = (float*)Cbase;
#pragma unroll
    for (int m = 0; m < 4; m++)
#pragma unroll
      for (int n = 0; n < 4; n++) {
        int row = rowBase + wr * 64 + m * 16 + lg * 4;
        int col = colBase + wc * 64 + n * 16 + lr;
#pragma unroll
        for (int r = 0; r < 4; r++)
          C[(size_t)(row + r) * DIM + col] = acc[m][n][r];
      }
  }
}

// ---------------- RoPE + head-layout ----------------
// QKVb: 3 x (MTOT x DIM) bf16. Writes Qh,Kh (bh, n, d) bf16 and Vt (bh, d, n) bf16.
__global__ __launch_bounds__(256) void rope_kernel(
    const u16* __restrict__ QKVb, const float2* __restrict__ cs,
    u16* __restrict__ Qh, u16* __restrict__ Kh, u16* __restrict__ Vt) {
  int nt = blockIdx.x;            // 0..31 (64-row tiles)
  int bh = blockIdx.y;            // 0..31
  int b = bh >> 4, h = bh & 15;
  __shared__ u16 vtile[64][66];
  int t = threadIdx.x;

  for (int tensor = 0; tensor < 3; ++tensor) {
    const u16* src = QKVb + (size_t)tensor * MTOT * DIM;
#pragma unroll 4
    for (int i = 0; i < 16; i++) {
      int idx = i * 256 + t;      // 0..4095
      int r = idx >> 6;
      int d = idx & 63;
      int n = nt * 64 + r;
      size_t gidx = ((size_t)(b * SEQ + n)) * DIM + h * 64;
      float v = b2f(src[gidx + d]);
      float out = v;
      if (d < 32) {
        float2 f = cs[n * 32 + d];
        float partner = b2f(src[gidx + ((d < 16) ? d + 16 : d - 16)]);
        out = (d < 16) ? (v * f.x - partner * f.y) : (v * f.x + partner * f.y);
      }
      if (tensor == 0) {
        Qh[((size_t)bh * SEQ + n) * 64 + d] = f2b(out * QSCALE);
      } else if (tensor == 1) {
        Kh[((size_t)bh * SEQ + n) * 64 + d] = f2b(out);
      } else {
        vtile[r][d] = f2b(out);
      }
    }
    if (tensor == 2) {
      __syncthreads();
#pragma unroll 4
      for (int i = 0; i < 16; i++) {
        int idx = i * 256 + t;
        int dd = idx >> 6;        // d
        int c = idx & 63;         // n within tile
        Vt[((size_t)bh * 64 + dd) * SEQ + nt * 64 + c] = vtile[c][dd];
      }
    }
  }
}

// ---------------- causal flash attention ----------------
// Block: (qt, bh). 4 waves x 16 q-rows = 64-row Q tile. K-tiles of 64.
__global__ __launch_bounds__(256) void attn_kernel(
    const u16* __restrict__ Qh, const u16* __restrict__ Kh,
    const u16* __restrict__ Vtg, u16* __restrict__ Ob) {
  int qt = blockIdx.x;           // 0..31
  int bh = blockIdx.y;           // 0..31
  int b = bh >> 4, h = bh & 15;
  __shared__ u16 Qs[64][64];
  __shared__ u16 Ks[64][64];
  __shared__ u16 Vs[64][64];     // [d][kpos]
  __shared__ u16 Ps[4][16][64];
  int t = threadIdx.x, w = t >> 6, l = t & 63;
  int lr = l & 15, lg = l >> 4;

  const u16* Qg = Qh + ((size_t)bh * SEQ + qt * 64) * 64;   // 8192B contiguous
#pragma unroll
  for (int i = 0; i < 2; i++) {
    int ob = t * 16 + i * 4096;
    gload_lds16((char*)Qs + ob, (const char*)Qg + ob);
  }
  __syncthreads();
  s16x8 qf[2];
#pragma unroll
  for (int kk = 0; kk < 2; kk++) qf[kk] = *(const s16x8*)&Qs[w * 16 + lr][kk * 32 + lg * 8];

  f32x4 o[4];
#pragma unroll
  for (int n = 0; n < 4; n++) o[n] = (f32x4){0.f, 0.f, 0.f, 0.f};
  float mrun[4], lsum[4];
#pragma unroll
  for (int r = 0; r < 4; r++) { mrun[r] = -3.0e38f; lsum[r] = 0.f; }

  for (int kt = 0; kt <= qt; ++kt) {
    __syncthreads();             // previous iter's LDS reads done
    const u16* Kg = Kh + ((size_t)bh * SEQ + kt * 64) * 64;
#pragma unroll
    for (int i = 0; i < 2; i++) {
      int ob = t * 16 + i * 4096;
      gload_lds16((char*)Ks + ob, (const char*)Kg + ob);
    }
#pragma unroll
    for (int i = 0; i < 2; i++) {
      int ob = t * 16 + i * 4096;
      int d = ob >> 7, cb = ob & 127;      // V rows are 128B
      gload_lds16((char*)Vs + ob,
                  (const char*)(Vtg + ((size_t)bh * 64 + d) * SEQ + kt * 64) + cb);
    }
    __syncthreads();

    // S = Q K^T  (scaled+log2e already folded into Q)
    f32x4 s[4];
#pragma unroll
    for (int n = 0; n < 4; n++) s[n] = (f32x4){0.f, 0.f, 0.f, 0.f};
#pragma unroll
    for (int n = 0; n < 4; n++)
#pragma unroll
      for (int kk = 0; kk < 2; kk++) {
        s16x8 bk = *(const s16x8*)&Ks[n * 16 + lr][kk * 32 + lg * 8];
        s[n] = __builtin_amdgcn_mfma_f32_16x16x32_bf16(qf[kk], bk, s[n], 0, 0, 0);
      }

    if (kt == qt) {              // causal mask on diagonal tile
#pragma unroll
      for (int n = 0; n < 4; n++) {
        int colb = n * 16 + lr;
#pragma unroll
        for (int r = 0; r < 4; r++) {
          int rowb = w * 16 + lg * 4 + r;
          if (colb > rowb) s[n][r] = -3.0e38f;
        }
      }
    }

    // online softmax (exp2 domain)
    float tm[4];
#pragma unroll
    for (int r = 0; r < 4; r++)
      tm[r] = fmaxf(fmaxf(s[0][r], s[1][r]), fmaxf(s[2][r], s[3][r]));
#pragma unroll
    for (int off = 1; off < 16; off <<= 1)
#pragma unroll
      for (int r = 0; r < 4; r++) tm[r] = fmaxf(tm[r], __shfl_xor(tm[r], off, 64));
    float alpha[4];
#pragma unroll
    for (int r = 0; r < 4; r++) {
      float mn = fmaxf(mrun[r], tm[r]);
      alpha[r] = exp2f(mrun[r] - mn);
      mrun[r] = mn;
      lsum[r] *= alpha[r];
    }
#pragma unroll
    for (int n = 0; n < 4; n++) {
#pragma unroll
      for (int r = 0; r < 4; r++) {
        float p = exp2f(s[n][r] - mrun[r]);
        lsum[r] += p;
        o[n][r] *= alpha[r];
        Ps[w][lg * 4 + r][n * 16 + lr] = f2b(p);
      }
    }
    __syncthreads();             // P visible to whole wave (and block)

    // O += P V   (A = P rows, B = Vs[d][k] col-fragments)
    s16x8 pa[2];
#pragma unroll
    for (int kk = 0; kk < 2; kk++) pa[kk] = *(const s16x8*)&Ps[w][lr][kk * 32 + lg * 8];
#pragma unroll
    for (int n = 0; n < 4; n++)
#pragma unroll
      for (int kk = 0; kk < 2; kk++) {
        s16x8 vb = *(const s16x8*)&Vs[n * 16 + lr][kk * 32 + lg * 8];
        o[n] = __builtin_amdgcn_mfma_f32_16x16x32_bf16(pa[kk], vb, o[n], 0, 0, 0);
      }
  }

  // finalize
#pragma unroll
  for (int off = 1; off < 16; off <<= 1)
#pragma unroll
    for (int r = 0; r < 4; r++) lsum[r] += __shfl_xor(lsum[r], off, 64);
  float inv[4];
#pragma unroll
  for (int r = 0; r < 4; r++) inv[r] = 1.0f / lsum[r];
#pragma unroll
  for (int n = 0; n < 4; n++)
#pragma unroll
    for (int r = 0; r < 4; r++) {
      int row = qt * 64 + w * 16 + lg * 4 + r;
      int col = h * 64 + n * 16 + lr;
      Ob[((size_t)b * SEQ + row) * DIM + col] = f2b(o[n][r] * inv[r]);
    }
}

// ---------------- launch ----------------
extern "C" void kernel_launch(void* const* d_in, const int* in_sizes, int n_in,
                              void* d_out, int out_size, void* d_ws, size_t ws_size,
                              hipStream_t stream) {
  (void)in_sizes; (void)n_in; (void)out_size; (void)ws_size;
  const float* x = (const float*)d_in[0];
  const float* rot = (const float*)d_in[1];
  const float* Wq = (const float*)d_in[2];
  const float* Wk = (const float*)d_in[3];
  const float* Wv = (const float*)d_in[4];
  const float* Wo = (const float*)d_in[5];

  char* ws = (char*)d_ws;
  u16* xb    = (u16*)(ws);                         // 8 MB
  u16* WtAll = (u16*)(ws + (8ll << 20));           // 8 MB (4 weights, B^T bf16)
  u16* QKVb  = (u16*)(ws + (16ll << 20));          // 24 MB
  u16* Qh    = (u16*)(ws + (40ll << 20));          // 8 MB
  u16* Kh    = (u16*)(ws + (48ll << 20));          // 8 MB
  u16* Vt    = (u16*)(ws + (56ll << 20));          // 8 MB
  u16* Ob    = (u16*)(ws + (64ll << 20));          // 8 MB
  float2* cs = (float2*)(ws + (72ll << 20));       // 0.5 MB

  cast_x_kernel<<<4096, 256, 0, stream>>>(x, xb);
  transw_kernel<<<dim3(32, 32, 4), dim3(32, 8), 0, stream>>>(Wq, Wk, Wv, Wo, WtAll);
  table_kernel<<<256, 256, 0, stream>>>(rot, cs);
  gemm128<true><<<dim3(32, 8, 3), 256, 0, stream>>>(xb, WtAll, QKVb);
  rope_kernel<<<dim3(32, 32), 256, 0, stream>>>(QKVb, cs, Qh, Kh, Vt);
  attn_kernel<<<dim3(32, 32), 256, 0, stream>>>(Qh, Kh, Vt, Ob);
  gemm128<false><<<dim3(32, 8, 1), 256, 0, stream>>>(Ob, WtAll + 3ll * DIM * DIM, d_out);
}

// Round 2
// 255.854 us; speedup vs baseline: 1.1773x; 1.1773x over previous
//
#include <hip/hip_runtime.h>
#include <hip/hip_bf16.h>
#include <stdint.h>

#define BATCH 2
#define SEQ 2048
#define NHEADS 16
#define DIM 1024
#define MTOT 4096            // BATCH*SEQ
#define LOG2E 1.4426950408889634f
#define QSCALE (0.125f * LOG2E)   // d^-0.5 * log2(e), folded into Q

typedef __attribute__((ext_vector_type(8))) short s16x8;   // 8 bf16
typedef __attribute__((ext_vector_type(4))) float f32x4;
typedef unsigned short u16;

__device__ __forceinline__ u16 f2b(float f) {
  union { float f; uint32_t u; } v; v.f = f;
  uint32_t r = v.u + 0x7FFFu + ((v.u >> 16) & 1u);
  return (u16)(r >> 16);
}
__device__ __forceinline__ float b2f(u16 h) {
  union { uint32_t u; float f; } v; v.u = ((uint32_t)h) << 16;
  return v.f;
}

// async global->LDS, 16B per lane. LDS dest must be uniform-base + lane*16.
__device__ __forceinline__ void gload_lds16(void* lds, const void* g) {
  __builtin_amdgcn_global_load_lds(
      (const __attribute__((address_space(1))) unsigned int*)g,
      (__attribute__((address_space(3))) unsigned int*)lds, 16, 0, 0);
}

// ---------------- prep kernels ----------------

__global__ __launch_bounds__(256) void cast_x_kernel(
    const float* __restrict__ x, u16* __restrict__ xb) {
  int i = (blockIdx.x * 256 + threadIdx.x) * 4;
  float4 v = *(const float4*)(x + i);
  ushort4 o;
  o.x = f2b(v.x); o.y = f2b(v.y); o.z = f2b(v.z); o.w = f2b(v.w);
  *(ushort4*)(xb + i) = o;
}

// W (K=1024 x N=1024) f32 -> Wt (N x K) bf16, z selects which weight
__global__ __launch_bounds__(256) void transw_kernel(
    const float* __restrict__ Wq, const float* __restrict__ Wk,
    const float* __restrict__ Wv, const float* __restrict__ Wo,
    u16* __restrict__ WtAll) {
  const float* W = (blockIdx.z == 0) ? Wq : (blockIdx.z == 1) ? Wk
                 : (blockIdx.z == 2) ? Wv : Wo;
  u16* Wt = WtAll + (size_t)blockIdx.z * DIM * DIM;
  __shared__ float t[32][33];
  int k0 = blockIdx.x * 32, n0 = blockIdx.y * 32;
  int tx = threadIdx.x, ty = threadIdx.y;   // (32,8)
#pragma unroll
  for (int i = 0; i < 4; i++) {
    int r = ty + i * 8;
    t[r][tx] = W[(size_t)(k0 + r) * DIM + n0 + tx];
  }
  __syncthreads();
#pragma unroll
  for (int i = 0; i < 4; i++) {
    int r = ty + i * 8;                      // output row = n
    Wt[(size_t)(n0 + r) * DIM + k0 + tx] = f2b(t[tx][r]);
  }
}

__global__ __launch_bounds__(256) void table_kernel(
    const float* __restrict__ rot, float2* __restrict__ cs) {
  int i = blockIdx.x * 256 + threadIdx.x;    // SEQ*32 = 65536
  float f = rot[i];
  float s, c;
  __sincosf(f, &s, &c);
  cs[i] = make_float2(c, s);
}

// ---------------- GEMM: C(M x N) = A(M x K) * Bt(N x K)^T ----------------
// 128x128 tile, BK=32, double-buffered LDS (1 barrier/iter), XOR-swizzled.
// MODE 0: QKV — z=0 rope->Qh, z=1 rope->Kh, z=2 plain bf16 -> Vb
// MODE 1: float output (out-projection)
template <int MODE>
__global__ __launch_bounds__(256) void gemm128(
    const u16* __restrict__ A, const u16* __restrict__ BtBase,
    void* __restrict__ Cbase, const float2* __restrict__ cs,
    u16* __restrict__ Qh, u16* __restrict__ Kh, u16* __restrict__ Vb) {
  __shared__ u16 Asm[2][128 * 32];
  __shared__ u16 Bsm[2][128 * 32];
  const u16* Bt = BtBase + (size_t)blockIdx.z * DIM * DIM;

  int t = threadIdx.x;
  int w = t >> 6, l = t & 63;
  int wr = w >> 1, wc = w & 1;
  int lr = l & 15, lg = l >> 4;
  int rowBase = blockIdx.x * 128;
  int colBase = blockIdx.y * 128;

  const char* Ab = (const char*)(A + (size_t)rowBase * DIM);
  const char* Bb = (const char*)(Bt + (size_t)colBase * DIM);

  f32x4 acc[4][4];
#pragma unroll
  for (int m = 0; m < 4; m++)
#pragma unroll
    for (int n = 0; n < 4; n++) acc[m][n] = (f32x4){0.f, 0.f, 0.f, 0.f};

  // stage 128x32 bf16 tiles; rows are 64B; swizzle: byte ^= ((row>>1)&3)<<4
  auto stage = [&](int buf, int kt) {
#pragma unroll
    for (int i = 0; i < 2; i++) {
      int ob = t * 16 + i * 4096;            // 8KB per tensor
      int row = ob >> 6, cb = ob & 63;
      int src = row * (DIM * 2) + kt * 64 + (cb ^ (((row >> 1) & 3) << 4));
      gload_lds16((char*)&Asm[buf][0] + ob, Ab + src);
      gload_lds16((char*)&Bsm[buf][0] + ob, Bb + src);
    }
  };

  stage(0, 0);
  for (int kt = 0; kt < DIM / 32; ++kt) {
    int cur = kt & 1;
    __syncthreads();                          // drains vmcnt -> buf cur ready
    if (kt + 1 < DIM / 32) stage(cur ^ 1, kt + 1);
    const char* ab = (const char*)&Asm[cur][0];
    const char* bb = (const char*)&Bsm[cur][0];
    s16x8 af[4], bf[4];
#pragma unroll
    for (int m = 0; m < 4; m++) {
      int R = wr * 64 + m * 16 + lr;
      af[m] = *(const s16x8*)(ab + R * 64 + ((lg * 16) ^ (((R >> 1) & 3) << 4)));
    }
#pragma unroll
    for (int n = 0; n < 4; n++) {
      int R = wc * 64 + n * 16 + lr;
      bf[n] = *(const s16x8*)(bb + R * 64 + ((lg * 16) ^ (((R >> 1) & 3) << 4)));
    }
    __builtin_amdgcn_s_setprio(1);
#pragma unroll
    for (int m = 0; m < 4; m++)
#pragma unroll
      for (int n = 0; n < 4; n++)
        acc[m][n] = __builtin_amdgcn_mfma_f32_16x16x32_bf16(af[m], bf[n], acc[m][n], 0, 0, 0);
    __builtin_amdgcn_s_setprio(0);
  }

  if constexpr (MODE == 1) {
    float* C = (float*)Cbase;
#pragma unroll
    for (int m = 0; m < 4; m++)
#pragma unroll
      for (int n = 0; n < 4; n++) {
        int row = rowBase + wr * 64 + m * 16 + lg * 4;
        int col = colBase + wc * 64 + n * 16 + lr;
#pragma unroll
        for (int r = 0; r < 4; r++)
          C[(size_t)(row + r) * DIM + col] = acc[m][n][r];
      }
  } else {
    int z = blockIdx.z;
    if (z == 2) {
      u16* C = Vb;
#pragma unroll
      for (int m = 0; m < 4; m++)
#pragma unroll
        for (int n = 0; n < 4; n++) {
          int row = rowBase + wr * 64 + m * 16 + lg * 4;
          int col = colBase + wc * 64 + n * 16 + lr;
#pragma unroll
          for (int r = 0; r < 4; r++)
            C[(size_t)(row + r) * DIM + col] = f2b(acc[m][n][r]);
        }
    } else {
      // fused RoPE epilogue: wave covers exactly one head (64 cols)
      u16* C = (z == 0) ? Qh : Kh;
      float sc = (z == 0) ? QSCALE : 1.0f;
      int h = (colBase + wc * 64) >> 6;
#pragma unroll
      for (int m = 0; m < 4; m++) {
#pragma unroll
        for (int r = 0; r < 4; r++) {
          int row = rowBase + wr * 64 + m * 16 + lg * 4 + r;
          int nrow = row & (SEQ - 1);
          int bb2 = row >> 11;
          const float2* csr = cs + (size_t)nrow * 32;
          float a0 = acc[m][0][r], a1 = acc[m][1][r];
          float2 f0 = csr[lr];        // d = lr
          float2 f1 = csr[16 + lr];   // d = 16+lr
          float o0 = (a0 * f0.x - a1 * f0.y) * sc;
          float o1 = (a1 * f1.x + a0 * f1.y) * sc;
          size_t base = ((size_t)(bb2 * NHEADS + h) * SEQ + nrow) * 64;
          C[base + lr]      = f2b(o0);
          C[base + 16 + lr] = f2b(o1);
          C[base + 32 + lr] = f2b(acc[m][2][r] * sc);
          C[base + 48 + lr] = f2b(acc[m][3][r] * sc);
        }
      }
    }
  }
}

// ---------------- V rope + transpose ----------------
// Vb (b*n, dim) bf16 -> rope -> Vt (bh, d, n) bf16
__global__ __launch_bounds__(256) void vrope_kernel(
    const u16* __restrict__ Vb, const float2* __restrict__ cs,
    u16* __restrict__ Vt) {
  int nt = blockIdx.x;            // 64-row tile
  int bh = blockIdx.y;
  int b = bh >> 4, h = bh & 15;
  __shared__ u16 vtile[64][66];
  int t = threadIdx.x;
#pragma unroll 4
  for (int i = 0; i < 16; i++) {
    int idx = i * 256 + t;
    int r = idx >> 6, d = idx & 63;
    int n = nt * 64 + r;
    size_t gidx = ((size_t)(b * SEQ + n)) * DIM + h * 64;
    float v = b2f(Vb[gidx + d]);
    float out = v;
    if (d < 32) {
      float2 f = cs[n * 32 + d];
      float partner = b2f(Vb[gidx + ((d < 16) ? d + 16 : d - 16)]);
      out = (d < 16) ? (v * f.x - partner * f.y) : (v * f.x + partner * f.y);
    }
    vtile[r][d] = f2b(out);
  }
  __syncthreads();
#pragma unroll 4
  for (int i = 0; i < 16; i++) {
    int idx = i * 256 + t;
    int dd = idx >> 6, c = idx & 63;
    Vt[((size_t)bh * 64 + dd) * SEQ + nt * 64 + c] = vtile[c][dd];
  }
}

// ---------------- causal flash attention ----------------
// 128 threads = 2 waves; each wave owns 16 q-rows (32-row Q tile / block).
// Block pi handles q-tiles pi and 63-pi sequentially -> exactly 33 kt-iters.
// K/V double-buffered in LDS, XOR-swizzled (pre-swizzled global source).
__global__ __launch_bounds__(128) void attn_kernel(
    const u16* __restrict__ Qh, const u16* __restrict__ Kh,
    const u16* __restrict__ Vtg, u16* __restrict__ Ob) {
  int pi = blockIdx.x;           // 0..31
  int bh = blockIdx.y;           // 0..31
  int b = bh >> 4, h = bh & 15;
  __shared__ u16 Ks[2][64 * 64];
  __shared__ u16 Vs[2][64 * 64];     // [d][kpos]
  __shared__ u16 Ps[2][16 * 64];
  int t = threadIdx.x, w = t >> 6, l = t & 63;
  int lr = l & 15, lg = l >> 4;
  char* psb = (char*)&Ps[w][0];

  const char* Kbh = (const char*)(Kh + (size_t)bh * SEQ * 64);
  const char* Vbh = (const char*)Vtg + (size_t)bh * 64 * SEQ * 2;
  const u16* Qbh = Qh + (size_t)bh * SEQ * 64;

  auto stage = [&](int buf, int kt) {
    const char* kg = Kbh + (size_t)kt * 64 * 128;   // K rows contiguous 128B
    const char* vg = Vbh + kt * 128;                // V rows stride SEQ*2
#pragma unroll
    for (int i = 0; i < 4; i++) {
      int ob = i * 2048 + t * 16;
      int row = ob >> 7, cb = ob & 127;
      int sw = cb ^ ((row & 7) << 4);
      gload_lds16((char*)&Ks[buf][0] + ob, kg + row * 128 + sw);
      gload_lds16((char*)&Vs[buf][0] + ob, vg + row * 4096 + sw);
    }
  };

#pragma unroll 1
  for (int ph = 0; ph < 2; ++ph) {
    int qt = ph ? (63 - pi) : pi;          // 32-row q tile index
    int nkt = (qt >> 1) + 1;
    int qrow0 = qt * 32 + w * 16;

    s16x8 qf[2];
#pragma unroll
    for (int kk = 0; kk < 2; kk++)
      qf[kk] = *(const s16x8*)(Qbh + (size_t)(qrow0 + lr) * 64 + kk * 32 + lg * 8);

    f32x4 o[4];
#pragma unroll
    for (int n = 0; n < 4; n++) o[n] = (f32x4){0.f, 0.f, 0.f, 0.f};
    float mrun[4], lsum[4];
#pragma unroll
    for (int r = 0; r < 4; r++) { mrun[r] = -3.0e38f; lsum[r] = 0.f; }

    __syncthreads();                       // prior phase LDS reads fully done
    stage(0, 0);
    for (int kt = 0; kt < nkt; ++kt) {
      int cur = kt & 1;
      __syncthreads();                     // drains vmcnt: buf cur staged
      if (kt + 1 < nkt) stage(cur ^ 1, kt + 1);
      const char* kb = (const char*)&Ks[cur][0];
      const char* vb = (const char*)&Vs[cur][0];

      // S = Q K^T (scale+log2e folded into Q)
      f32x4 s[4];
#pragma unroll
      for (int n = 0; n < 4; n++) s[n] = (f32x4){0.f, 0.f, 0.f, 0.f};
      __builtin_amdgcn_s_setprio(1);
#pragma unroll
      for (int n = 0; n < 4; n++)
#pragma unroll
        for (int kk = 0; kk < 2; kk++) {
          int R = n * 16 + lr;
          s16x8 bk = *(const s16x8*)(kb + R * 128 + ((kk * 64 + lg * 16) ^ ((R & 7) << 4)));
          s[n] = __builtin_amdgcn_mfma_f32_16x16x32_bf16(qf[kk], bk, s[n], 0, 0, 0);
        }
      __builtin_amdgcn_s_setprio(0);

      if (kt == nkt - 1) {                 // causal mask (diagonal tile)
#pragma unroll
        for (int n = 0; n < 4; n++) {
          int colg = kt * 64 + n * 16 + lr;
#pragma unroll
          for (int r = 0; r < 4; r++) {
            int rowg = qt * 32 + w * 16 + lg * 4 + r;
            if (colg > rowg) s[n][r] = -3.0e38f;
          }
        }
      }

      // online softmax (exp2 domain)
      float tm[4];
#pragma unroll
      for (int r = 0; r < 4; r++)
        tm[r] = fmaxf(fmaxf(s[0][r], s[1][r]), fmaxf(s[2][r], s[3][r]));
#pragma unroll
      for (int off = 1; off < 16; off <<= 1)
#pragma unroll
        for (int r = 0; r < 4; r++) tm[r] = fmaxf(tm[r], __shfl_xor(tm[r], off, 64));
      float alpha[4];
#pragma unroll
      for (int r = 0; r < 4; r++) {
        float mn = fmaxf(mrun[r], tm[r]);
        alpha[r] = exp2f(mrun[r] - mn);
        mrun[r] = mn;
        lsum[r] *= alpha[r];
      }
#pragma unroll
      for (int n = 0; n < 4; n++) {
#pragma unroll
        for (int r = 0; r < 4; r++) {
          float p = exp2f(s[n][r] - mrun[r]);
          lsum[r] += p;
          o[n][r] *= alpha[r];
          int prow = lg * 4 + r;
          *(u16*)(psb + prow * 128 + (((n * 16 + lr) * 2) ^ ((prow & 7) << 4))) = f2b(p);
        }
      }
      // P is per-wave only: no barrier needed (compiler inserts lgkm waits)

      s16x8 pa[2];
#pragma unroll
      for (int kk = 0; kk < 2; kk++)
        pa[kk] = *(const s16x8*)(psb + lr * 128 + ((kk * 64 + lg * 16) ^ ((lr & 7) << 4)));
      __builtin_amdgcn_s_setprio(1);
#pragma unroll
      for (int n = 0; n < 4; n++)
#pragma unroll
        for (int kk = 0; kk < 2; kk++) {
          int R = n * 16 + lr;
          s16x8 vv = *(const s16x8*)(vb + R * 128 + ((kk * 64 + lg * 16) ^ ((R & 7) << 4)));
          o[n] = __builtin_amdgcn_mfma_f32_16x16x32_bf16(pa[kk], vv, o[n], 0, 0, 0);
        }
      __builtin_amdgcn_s_setprio(0);
    }

    // finalize this q-tile
#pragma unroll
    for (int off = 1; off < 16; off <<= 1)
#pragma unroll
      for (int r = 0; r < 4; r++) lsum[r] += __shfl_xor(lsum[r], off, 64);
    float inv[4];
#pragma unroll
    for (int r = 0; r < 4; r++) inv[r] = 1.0f / lsum[r];
#pragma unroll
    for (int n = 0; n < 4; n++)
#pragma unroll
      for (int r = 0; r < 4; r++) {
        int rowg = qt * 32 + w * 16 + lg * 4 + r;
        int col = h * 64 + n * 16 + lr;
        Ob[((size_t)b * SEQ + rowg) * DIM + col] = f2b(o[n][r] * inv[r]);
      }
  }
}

// ---------------- launch ----------------
extern "C" void kernel_launch(void* const* d_in, const int* in_sizes, int n_in,
                              void* d_out, int out_size, void* d_ws, size_t ws_size,
                              hipStream_t stream) {
  (void)in_sizes; (void)n_in; (void)out_size; (void)ws_size;
  const float* x = (const float*)d_in[0];
  const float* rot = (const float*)d_in[1];
  const float* Wq = (const float*)d_in[2];
  const float* Wk = (const float*)d_in[3];
  const float* Wv = (const float*)d_in[4];
  const float* Wo = (const float*)d_in[5];

  char* ws = (char*)d_ws;
  u16* xb    = (u16*)(ws);                         // 8 MB
  u16* WtAll = (u16*)(ws + (8ll << 20));           // 8 MB
  u16* Vb    = (u16*)(ws + (16ll << 20));          // 8 MB
  u16* Qh    = (u16*)(ws + (24ll << 20));          // 8 MB
  u16* Kh    = (u16*)(ws + (32ll << 20));          // 8 MB
  u16* Vt    = (u16*)(ws + (40ll << 20));          // 8 MB
  u16* Ob    = (u16*)(ws + (48ll << 20));          // 8 MB
  float2* cs = (float2*)(ws + (56ll << 20));       // 0.5 MB

  cast_x_kernel<<<4096, 256, 0, stream>>>(x, xb);
  transw_kernel<<<dim3(32, 32, 4), dim3(32, 8), 0, stream>>>(Wq, Wk, Wv, Wo, WtAll);
  table_kernel<<<256, 256, 0, stream>>>(rot, cs);
  gemm128<0><<<dim3(32, 8, 3), 256, 0, stream>>>(xb, WtAll, nullptr, cs, Qh, Kh, Vb);
  vrope_kernel<<<dim3(32, 32), 256, 0, stream>>>(Vb, cs, Vt);
  attn_kernel<<<dim3(32, 32), 128, 0, stream>>>(Qh, Kh, Vt, Ob);
  gemm128<1><<<dim3(32, 8, 1), 256, 0, stream>>>(Ob, WtAll + 3ll * DIM * DIM, d_out,
                                                 nullptr, nullptr, nullptr, nullptr);
}

// Round 3
// 233.830 us; speedup vs baseline: 1.2882x; 1.0942x over previous
//
#include <hip/hip_runtime.h>
#include <hip/hip_bf16.h>
#include <stdint.h>

#define BATCH 2
#define SEQ 2048
#define NHEADS 16
#define DIM 1024
#define MTOT 4096            // BATCH*SEQ
#define LOG2E 1.4426950408889634f
#define QSCALE (0.125f * LOG2E)   // d^-0.5 * log2(e), folded into Q
#define DEFER_THR 11.54f          // 8 * log2(e): defer-max threshold (exp2 domain)

typedef __attribute__((ext_vector_type(8))) short s16x8;   // 8 bf16
typedef __attribute__((ext_vector_type(4))) float f32x4;
typedef unsigned short u16;

__device__ __forceinline__ u16 f2b(float f) {
  union { float f; uint32_t u; } v; v.f = f;
  uint32_t r = v.u + 0x7FFFu + ((v.u >> 16) & 1u);
  return (u16)(r >> 16);
}
__device__ __forceinline__ float b2f(u16 h) {
  union { uint32_t u; float f; } v; v.u = ((uint32_t)h) << 16;
  return v.f;
}

// async global->LDS, 16B per lane. LDS dest must be uniform-base + lane*16.
__device__ __forceinline__ void gload_lds16(void* lds, const void* g) {
  __builtin_amdgcn_global_load_lds(
      (const __attribute__((address_space(1))) unsigned int*)g,
      (__attribute__((address_space(3))) unsigned int*)lds, 16, 0, 0);
}

// ---------------- prep kernels ----------------

__global__ __launch_bounds__(256) void cast_x_kernel(
    const float* __restrict__ x, u16* __restrict__ xb) {
  int i = (blockIdx.x * 256 + threadIdx.x) * 4;
  float4 v = *(const float4*)(x + i);
  ushort4 o;
  o.x = f2b(v.x); o.y = f2b(v.y); o.z = f2b(v.z); o.w = f2b(v.w);
  *(ushort4*)(xb + i) = o;
}

// W (K=1024 x N=1024) f32 -> Wt (N x K) bf16, z selects which weight
__global__ __launch_bounds__(256) void transw_kernel(
    const float* __restrict__ Wq, const float* __restrict__ Wk,
    const float* __restrict__ Wv, const float* __restrict__ Wo,
    u16* __restrict__ WtAll) {
  const float* W = (blockIdx.z == 0) ? Wq : (blockIdx.z == 1) ? Wk
                 : (blockIdx.z == 2) ? Wv : Wo;
  u16* Wt = WtAll + (size_t)blockIdx.z * DIM * DIM;
  __shared__ float t[32][33];
  int k0 = blockIdx.x * 32, n0 = blockIdx.y * 32;
  int tx = threadIdx.x, ty = threadIdx.y;   // (32,8)
#pragma unroll
  for (int i = 0; i < 4; i++) {
    int r = ty + i * 8;
    t[r][tx] = W[(size_t)(k0 + r) * DIM + n0 + tx];
  }
  __syncthreads();
#pragma unroll
  for (int i = 0; i < 4; i++) {
    int r = ty + i * 8;                      // output row = n
    Wt[(size_t)(n0 + r) * DIM + k0 + tx] = f2b(t[tx][r]);
  }
}

__global__ __launch_bounds__(256) void table_kernel(
    const float* __restrict__ rot, float2* __restrict__ cs) {
  int i = blockIdx.x * 256 + threadIdx.x;    // SEQ*32 = 65536
  float f = rot[i];
  float s, c;
  __sincosf(f, &s, &c);
  cs[i] = make_float2(c, s);
}

// ---------------- GEMM: C(M x N) = A(M x K) * Bt(N x K)^T ----------------
// 128x128 tile, BK=32, double-buffered LDS (1 barrier/iter), XOR-swizzled.
// MODE 0: QKV — z=0 rope->Qh, z=1 rope->Kh, z=2 rope+transpose->Vt
// MODE 1: float output (out-projection)
template <int MODE>
__global__ __launch_bounds__(256) void gemm128(
    const u16* __restrict__ A, const u16* __restrict__ BtBase,
    void* __restrict__ Cbase, const float2* __restrict__ cs,
    u16* __restrict__ Qh, u16* __restrict__ Kh, u16* __restrict__ Vt) {
  __shared__ u16 Asm[2][128 * 32];
  __shared__ u16 Bsm[2][128 * 32];
  const u16* Bt = BtBase + (size_t)blockIdx.z * DIM * DIM;

  int t = threadIdx.x;
  int w = t >> 6, l = t & 63;
  int wr = w >> 1, wc = w & 1;
  int lr = l & 15, lg = l >> 4;
  int rowBase = blockIdx.x * 128;
  int colBase = blockIdx.y * 128;

  const char* Ab = (const char*)(A + (size_t)rowBase * DIM);
  const char* Bb = (const char*)(Bt + (size_t)colBase * DIM);

  f32x4 acc[4][4];
#pragma unroll
  for (int m = 0; m < 4; m++)
#pragma unroll
    for (int n = 0; n < 4; n++) acc[m][n] = (f32x4){0.f, 0.f, 0.f, 0.f};

  // stage 128x32 bf16 tiles; rows are 64B; swizzle: byte ^= ((row>>1)&3)<<4
  auto stage = [&](int buf, int kt) {
#pragma unroll
    for (int i = 0; i < 2; i++) {
      int ob = t * 16 + i * 4096;            // 8KB per tensor
      int row = ob >> 6, cb = ob & 63;
      int src = row * (DIM * 2) + kt * 64 + (cb ^ (((row >> 1) & 3) << 4));
      gload_lds16((char*)&Asm[buf][0] + ob, Ab + src);
      gload_lds16((char*)&Bsm[buf][0] + ob, Bb + src);
    }
  };

  stage(0, 0);
  for (int kt = 0; kt < DIM / 32; ++kt) {
    int cur = kt & 1;
    __syncthreads();                          // drains vmcnt -> buf cur ready
    if (kt + 1 < DIM / 32) stage(cur ^ 1, kt + 1);
    const char* ab = (const char*)&Asm[cur][0];
    const char* bb = (const char*)&Bsm[cur][0];
    s16x8 af[4], bf[4];
#pragma unroll
    for (int m = 0; m < 4; m++) {
      int R = wr * 64 + m * 16 + lr;
      af[m] = *(const s16x8*)(ab + R * 64 + ((lg * 16) ^ (((R >> 1) & 3) << 4)));
    }
#pragma unroll
    for (int n = 0; n < 4; n++) {
      int R = wc * 64 + n * 16 + lr;
      bf[n] = *(const s16x8*)(bb + R * 64 + ((lg * 16) ^ (((R >> 1) & 3) << 4)));
    }
    __builtin_amdgcn_s_setprio(1);
#pragma unroll
    for (int m = 0; m < 4; m++)
#pragma unroll
      for (int n = 0; n < 4; n++)
        acc[m][n] = __builtin_amdgcn_mfma_f32_16x16x32_bf16(af[m], bf[n], acc[m][n], 0, 0, 0);
    __builtin_amdgcn_s_setprio(0);
  }

  if constexpr (MODE == 1) {
    float* C = (float*)Cbase;
#pragma unroll
    for (int m = 0; m < 4; m++)
#pragma unroll
      for (int n = 0; n < 4; n++) {
        int row = rowBase + wr * 64 + m * 16 + lg * 4;
        int col = colBase + wc * 64 + n * 16 + lr;
#pragma unroll
        for (int r = 0; r < 4; r++)
          C[(size_t)(row + r) * DIM + col] = acc[m][n][r];
      }
  } else {
    int z = blockIdx.z;
    int h = (colBase + wc * 64) >> 6;          // wave covers exactly one head
    if (z == 2) {
      // fused RoPE + transpose epilogue -> Vt (bh, d, n)
#pragma unroll
      for (int m = 0; m < 4; m++) {
#pragma unroll
        for (int r = 0; r < 4; r++) {
          int row = rowBase + wr * 64 + m * 16 + lg * 4 + r;
          int nrow = row & (SEQ - 1);
          int b2 = row >> 11;
          const float2* csr = cs + (size_t)nrow * 32;
          float a0 = acc[m][0][r], a1 = acc[m][1][r];
          float2 f0 = csr[lr];
          float2 f1 = csr[16 + lr];
          float o0 = a0 * f0.x - a1 * f0.y;
          float o1 = a1 * f1.x + a0 * f1.y;
          size_t vbase = ((size_t)(b2 * NHEADS + h) * 64) * SEQ + nrow;
          Vt[vbase + (size_t)lr * SEQ]        = f2b(o0);
          Vt[vbase + (size_t)(16 + lr) * SEQ] = f2b(o1);
          Vt[vbase + (size_t)(32 + lr) * SEQ] = f2b(acc[m][2][r]);
          Vt[vbase + (size_t)(48 + lr) * SEQ] = f2b(acc[m][3][r]);
        }
      }
    } else {
      // fused RoPE epilogue -> Qh / Kh (bh, n, d)
      u16* C = (z == 0) ? Qh : Kh;
      float sc = (z == 0) ? QSCALE : 1.0f;
#pragma unroll
      for (int m = 0; m < 4; m++) {
#pragma unroll
        for (int r = 0; r < 4; r++) {
          int row = rowBase + wr * 64 + m * 16 + lg * 4 + r;
          int nrow = row & (SEQ - 1);
          int b2 = row >> 11;
          const float2* csr = cs + (size_t)nrow * 32;
          float a0 = acc[m][0][r], a1 = acc[m][1][r];
          float2 f0 = csr[lr];        // d = lr
          float2 f1 = csr[16 + lr];   // d = 16+lr
          float o0 = (a0 * f0.x - a1 * f0.y) * sc;
          float o1 = (a1 * f1.x + a0 * f1.y) * sc;
          size_t base = ((size_t)(b2 * NHEADS + h) * SEQ + nrow) * 64;
          C[base + lr]      = f2b(o0);
          C[base + 16 + lr] = f2b(o1);
          C[base + 32 + lr] = f2b(acc[m][2][r] * sc);
          C[base + 48 + lr] = f2b(acc[m][3][r] * sc);
        }
      }
    }
  }
}

// ---------------- causal flash attention ----------------
// 128 threads = 2 waves; each wave owns 16 q-rows (32-row Q tile / block).
// Block pi handles q-tiles pi and 63-pi sequentially -> exactly 33 kt-iters.
// XCD-aware remap: each XCD owns 4 bh entirely -> K/V L2-resident (2MB/XCD).
__global__ __launch_bounds__(128) void attn_kernel(
    const u16* __restrict__ Qh, const u16* __restrict__ Kh,
    const u16* __restrict__ Vtg, u16* __restrict__ Ob) {
  int id = blockIdx.y * 32 + blockIdx.x;   // 0..1023
  int xcd = id & 7, within = id >> 3;      // XCD = id % 8 (round-robin dispatch)
  int bh = xcd * 4 + (within >> 5);        // 4 bh per XCD
  int pi = within & 31;
  int b = bh >> 4, h = bh & 15;
  __shared__ u16 Ks[2][64 * 64];
  __shared__ u16 Vs[2][64 * 64];     // [d][kpos]
  __shared__ u16 Ps[2][16 * 64];
  int t = threadIdx.x, w = t >> 6, l = t & 63;
  int lr = l & 15, lg = l >> 4;
  char* psb = (char*)&Ps[w][0];

  const char* Kbh = (const char*)(Kh + (size_t)bh * SEQ * 64);
  const char* Vbh = (const char*)Vtg + (size_t)bh * 64 * SEQ * 2;
  const u16* Qbh = Qh + (size_t)bh * SEQ * 64;

  auto stage = [&](int buf, int kt) {
    const char* kg = Kbh + (size_t)kt * 64 * 128;   // K rows contiguous 128B
    const char* vg = Vbh + kt * 128;                // V rows stride SEQ*2
#pragma unroll
    for (int i = 0; i < 4; i++) {
      int ob = i * 2048 + t * 16;
      int row = ob >> 7, cb = ob & 127;
      int sw = cb ^ ((row & 7) << 4);
      gload_lds16((char*)&Ks[buf][0] + ob, kg + row * 128 + sw);
      gload_lds16((char*)&Vs[buf][0] + ob, vg + row * 4096 + sw);
    }
  };

#pragma unroll 1
  for (int ph = 0; ph < 2; ++ph) {
    int qt = ph ? (63 - pi) : pi;          // 32-row q tile index
    int nkt = (qt >> 1) + 1;
    int qrow0 = qt * 32 + w * 16;

    s16x8 qf[2];
#pragma unroll
    for (int kk = 0; kk < 2; kk++)
      qf[kk] = *(const s16x8*)(Qbh + (size_t)(qrow0 + lr) * 64 + kk * 32 + lg * 8);

    f32x4 o[4];
#pragma unroll
    for (int n = 0; n < 4; n++) o[n] = (f32x4){0.f, 0.f, 0.f, 0.f};
    float mrun[4], lsum[4];
#pragma unroll
    for (int r = 0; r < 4; r++) { mrun[r] = -3.0e38f; lsum[r] = 0.f; }

    __syncthreads();                       // prior phase LDS reads fully done
    stage(0, 0);
    for (int kt = 0; kt < nkt; ++kt) {
      int cur = kt & 1;
      __syncthreads();                     // drains vmcnt: buf cur staged
      if (kt + 1 < nkt) stage(cur ^ 1, kt + 1);
      const char* kb = (const char*)&Ks[cur][0];
      const char* vb = (const char*)&Vs[cur][0];

      // S = Q K^T (scale+log2e folded into Q)
      f32x4 s[4];
#pragma unroll
      for (int n = 0; n < 4; n++) s[n] = (f32x4){0.f, 0.f, 0.f, 0.f};
      __builtin_amdgcn_s_setprio(1);
#pragma unroll
      for (int n = 0; n < 4; n++)
#pragma unroll
        for (int kk = 0; kk < 2; kk++) {
          int R = n * 16 + lr;
          s16x8 bk = *(const s16x8*)(kb + R * 128 + ((kk * 64 + lg * 16) ^ ((R & 7) << 4)));
          s[n] = __builtin_amdgcn_mfma_f32_16x16x32_bf16(qf[kk], bk, s[n], 0, 0, 0);
        }
      __builtin_amdgcn_s_setprio(0);

      if (kt == nkt - 1) {                 // causal mask (diagonal tile)
#pragma unroll
        for (int n = 0; n < 4; n++) {
          int colg = kt * 64 + n * 16 + lr;
#pragma unroll
          for (int r = 0; r < 4; r++) {
            int rowg = qt * 32 + w * 16 + lg * 4 + r;
            if (colg > rowg) s[n][r] = -3.0e38f;
          }
        }
      }

      // online softmax (exp2 domain) with defer-max (T13)
      float tm[4];
#pragma unroll
      for (int r = 0; r < 4; r++)
        tm[r] = fmaxf(fmaxf(s[0][r], s[1][r]), fmaxf(s[2][r], s[3][r]));
#pragma unroll
      for (int off = 1; off < 16; off <<= 1)
#pragma unroll
        for (int r = 0; r < 4; r++) tm[r] = fmaxf(tm[r], __shfl_xor(tm[r], off, 64));
      float need = 0.f;
#pragma unroll
      for (int r = 0; r < 4; r++) need = fmaxf(need, tm[r] - mrun[r]);
      if (!__all(need <= DEFER_THR)) {
        float alpha[4];
#pragma unroll
        for (int r = 0; r < 4; r++) {
          float mn = fmaxf(mrun[r], tm[r]);
          alpha[r] = exp2f(mrun[r] - mn);
          mrun[r] = mn;
          lsum[r] *= alpha[r];
        }
#pragma unroll
        for (int n = 0; n < 4; n++)
#pragma unroll
          for (int r = 0; r < 4; r++) o[n][r] *= alpha[r];
      }
#pragma unroll
      for (int n = 0; n < 4; n++) {
#pragma unroll
        for (int r = 0; r < 4; r++) {
          float p = exp2f(s[n][r] - mrun[r]);
          lsum[r] += p;
          int prow = lg * 4 + r;
          *(u16*)(psb + prow * 128 + (((n * 16 + lr) * 2) ^ ((prow & 7) << 4))) = f2b(p);
        }
      }
      // P is per-wave only: no barrier needed (compiler inserts lgkm waits)

      s16x8 pa[2];
#pragma unroll
      for (int kk = 0; kk < 2; kk++)
        pa[kk] = *(const s16x8*)(psb + lr * 128 + ((kk * 64 + lg * 16) ^ ((lr & 7) << 4)));
      __builtin_amdgcn_s_setprio(1);
#pragma unroll
      for (int n = 0; n < 4; n++)
#pragma unroll
        for (int kk = 0; kk < 2; kk++) {
          int R = n * 16 + lr;
          s16x8 vv = *(const s16x8*)(vb + R * 128 + ((kk * 64 + lg * 16) ^ ((R & 7) << 4)));
          o[n] = __builtin_amdgcn_mfma_f32_16x16x32_bf16(pa[kk], vv, o[n], 0, 0, 0);
        }
      __builtin_amdgcn_s_setprio(0);
    }

    // finalize this q-tile
#pragma unroll
    for (int off = 1; off < 16; off <<= 1)
#pragma unroll
      for (int r = 0; r < 4; r++) lsum[r] += __shfl_xor(lsum[r], off, 64);
    float inv[4];
#pragma unroll
    for (int r = 0; r < 4; r++) inv[r] = 1.0f / lsum[r];
#pragma unroll
    for (int n = 0; n < 4; n++)
#pragma unroll
      for (int r = 0; r < 4; r++) {
        int rowg = qt * 32 + w * 16 + lg * 4 + r;
        int col = h * 64 + n * 16 + lr;
        Ob[((size_t)b * SEQ + rowg) * DIM + col] = f2b(o[n][r] * inv[r]);
      }
  }
}

// ---------------- launch ----------------
extern "C" void kernel_launch(void* const* d_in, const int* in_sizes, int n_in,
                              void* d_out, int out_size, void* d_ws, size_t ws_size,
                              hipStream_t stream) {
  (void)in_sizes; (void)n_in; (void)out_size; (void)ws_size;
  const float* x = (const float*)d_in[0];
  const float* rot = (const float*)d_in[1];
  const float* Wq = (const float*)d_in[2];
  const float* Wk = (const float*)d_in[3];
  const float* Wv = (const float*)d_in[4];
  const float* Wo = (const float*)d_in[5];

  char* ws = (char*)d_ws;
  u16* xb    = (u16*)(ws);                         // 8 MB
  u16* WtAll = (u16*)(ws + (8ll << 20));           // 8 MB
  u16* Qh    = (u16*)(ws + (16ll << 20));          // 8 MB
  u16* Kh    = (u16*)(ws + (24ll << 20));          // 8 MB
  u16* Vt    = (u16*)(ws + (32ll << 20));          // 8 MB
  u16* Ob    = (u16*)(ws + (40ll << 20));          // 8 MB
  float2* cs = (float2*)(ws + (48ll << 20));       // 0.5 MB

  cast_x_kernel<<<4096, 256, 0, stream>>>(x, xb);
  transw_kernel<<<dim3(32, 32, 4), dim3(32, 8), 0, stream>>>(Wq, Wk, Wv, Wo, WtAll);
  table_kernel<<<256, 256, 0, stream>>>(rot, cs);
  gemm128<0><<<dim3(32, 8, 3), 256, 0, stream>>>(xb, WtAll, nullptr, cs, Qh, Kh, Vt);
  attn_kernel<<<dim3(32, 32), 128, 0, stream>>>(Qh, Kh, Vt, Ob);
  gemm128<1><<<dim3(32, 8, 1), 256, 0, stream>>>(Ob, WtAll + 3ll * DIM * DIM, d_out,
                                                 nullptr, nullptr, nullptr, nullptr);
}

// Round 4
// 212.522 us; speedup vs baseline: 1.4173x; 1.1003x over previous
//
#include <hip/hip_runtime.h>
#include <hip/hip_bf16.h>
#include <stdint.h>

#define BATCH 2
#define SEQ 2048
#define NHEADS 16
#define DIM 1024
#define MTOT 4096            // BATCH*SEQ
#define LOG2E 1.4426950408889634f
#define QSCALE (0.125f * LOG2E)   // d^-0.5 * log2(e), folded into Q
#define DEFER_THR 11.54f          // 8 * log2(e): defer-max threshold (exp2 domain)

typedef __attribute__((ext_vector_type(8))) short s16x8;   // 8 bf16
typedef __attribute__((ext_vector_type(4))) float f32x4;
typedef unsigned short u16;

__device__ __forceinline__ u16 f2b(float f) {       // RNE (epilogues)
  union { float f; uint32_t u; } v; v.f = f;
  uint32_t r = v.u + 0x7FFFu + ((v.u >> 16) & 1u);
  return (u16)(r >> 16);
}
__device__ __forceinline__ u16 f2b_fast(float f) {  // round-nearest-up (P path)
  union { float f; uint32_t u; } v; v.f = f;
  return (u16)((v.u + 0x8000u) >> 16);
}
__device__ __forceinline__ float b2f(u16 h) {
  union { uint32_t u; float f; } v; v.u = ((uint32_t)h) << 16;
  return v.f;
}

// async global->LDS, 16B per lane. LDS dest must be uniform-base + lane*16.
__device__ __forceinline__ void gload_lds16(void* lds, const void* g) {
  __builtin_amdgcn_global_load_lds(
      (const __attribute__((address_space(1))) unsigned int*)g,
      (__attribute__((address_space(3))) unsigned int*)lds, 16, 0, 0);
}

// ---------------- fused prep: cast x, transpose weights, cos/sin table ----
__global__ __launch_bounds__(256) void prep_kernel(
    const float* __restrict__ x, const float* __restrict__ Wq,
    const float* __restrict__ Wk, const float* __restrict__ Wv,
    const float* __restrict__ Wo, const float* __restrict__ rot,
    u16* __restrict__ xb, u16* __restrict__ WtAll, float2* __restrict__ cs) {
  __shared__ float tile[32][33];
  int bid = blockIdx.x, t = threadIdx.x;
  if (bid < 4096) {                          // cast x -> bf16
    int i = (bid * 256 + t) * 4;
    float4 v = *(const float4*)(x + i);
    ushort4 o;
    o.x = f2b(v.x); o.y = f2b(v.y); o.z = f2b(v.z); o.w = f2b(v.w);
    *(ushort4*)(xb + i) = o;
  } else if (bid < 8192) {                   // W -> W^T bf16
    int bb = bid - 4096;
    int z = bb >> 10, xB = bb & 31, yB = (bb >> 5) & 31;
    const float* W = (z == 0) ? Wq : (z == 1) ? Wk : (z == 2) ? Wv : Wo;
    u16* Wt = WtAll + (size_t)z * DIM * DIM;
    int k0 = xB * 32, n0 = yB * 32;
    int tx = t & 31, ty = t >> 5;
#pragma unroll
    for (int i = 0; i < 4; i++) {
      int r = ty + i * 8;
      tile[r][tx] = W[(size_t)(k0 + r) * DIM + n0 + tx];
    }
    __syncthreads();
#pragma unroll
    for (int i = 0; i < 4; i++) {
      int r = ty + i * 8;
      Wt[(size_t)(n0 + r) * DIM + k0 + tx] = f2b(tile[tx][r]);
    }
  } else {                                   // cos/sin table
    int i = (bid - 8192) * 256 + t;          // SEQ*32 = 65536
    float f = rot[i];
    float s, c;
    __sincosf(f, &s, &c);
    cs[i] = make_float2(c, s);
  }
}

// ---------------- GEMM: C(M x N) = A(M x K) * Bt(N x K)^T ----------------
// 128x128 tile, BK=32, double-buffered LDS (1 barrier/iter), XOR-swizzled.
// MODE 0: QKV — z=0 rope->Qh, z=1 rope->Kh, z=2 rope+transpose->Vt
// MODE 1: float output (out-projection)
template <int MODE>
__global__ __launch_bounds__(256) void gemm128(
    const u16* __restrict__ A, const u16* __restrict__ BtBase,
    void* __restrict__ Cbase, const float2* __restrict__ cs,
    u16* __restrict__ Qh, u16* __restrict__ Kh, u16* __restrict__ Vt) {
  __shared__ u16 Asm[2][128 * 32];
  __shared__ u16 Bsm[2][128 * 32];
  const u16* Bt = BtBase + (size_t)blockIdx.z * DIM * DIM;

  int t = threadIdx.x;
  int w = t >> 6, l = t & 63;
  int wr = w >> 1, wc = w & 1;
  int lr = l & 15, lg = l >> 4;
  int rowBase = blockIdx.x * 128;
  int colBase = blockIdx.y * 128;

  const char* Ab = (const char*)(A + (size_t)rowBase * DIM);
  const char* Bb = (const char*)(Bt + (size_t)colBase * DIM);

  f32x4 acc[4][4];
#pragma unroll
  for (int m = 0; m < 4; m++)
#pragma unroll
    for (int n = 0; n < 4; n++) acc[m][n] = (f32x4){0.f, 0.f, 0.f, 0.f};

  // stage 128x32 bf16 tiles; rows are 64B; swizzle: byte ^= ((row>>1)&3)<<4
  auto stage = [&](int buf, int kt) {
#pragma unroll
    for (int i = 0; i < 2; i++) {
      int ob = t * 16 + i * 4096;            // 8KB per tensor
      int row = ob >> 6, cb = ob & 63;
      int src = row * (DIM * 2) + kt * 64 + (cb ^ (((row >> 1) & 3) << 4));
      gload_lds16((char*)&Asm[buf][0] + ob, Ab + src);
      gload_lds16((char*)&Bsm[buf][0] + ob, Bb + src);
    }
  };

  stage(0, 0);
  for (int kt = 0; kt < DIM / 32; ++kt) {
    int cur = kt & 1;
    __syncthreads();                          // drains vmcnt -> buf cur ready
    if (kt + 1 < DIM / 32) stage(cur ^ 1, kt + 1);
    const char* ab = (const char*)&Asm[cur][0];
    const char* bb = (const char*)&Bsm[cur][0];
    s16x8 af[4], bf[4];
#pragma unroll
    for (int m = 0; m < 4; m++) {
      int R = wr * 64 + m * 16 + lr;
      af[m] = *(const s16x8*)(ab + R * 64 + ((lg * 16) ^ (((R >> 1) & 3) << 4)));
    }
#pragma unroll
    for (int n = 0; n < 4; n++) {
      int R = wc * 64 + n * 16 + lr;
      bf[n] = *(const s16x8*)(bb + R * 64 + ((lg * 16) ^ (((R >> 1) & 3) << 4)));
    }
    __builtin_amdgcn_s_setprio(1);
#pragma unroll
    for (int m = 0; m < 4; m++)
#pragma unroll
      for (int n = 0; n < 4; n++)
        acc[m][n] = __builtin_amdgcn_mfma_f32_16x16x32_bf16(af[m], bf[n], acc[m][n], 0, 0, 0);
    __builtin_amdgcn_s_setprio(0);
  }

  if constexpr (MODE == 1) {
    float* C = (float*)Cbase;
#pragma unroll
    for (int m = 0; m < 4; m++)
#pragma unroll
      for (int n = 0; n < 4; n++) {
        int row = rowBase + wr * 64 + m * 16 + lg * 4;
        int col = colBase + wc * 64 + n * 16 + lr;
#pragma unroll
        for (int r = 0; r < 4; r++)
          C[(size_t)(row + r) * DIM + col] = acc[m][n][r];
      }
  } else {
    int z = blockIdx.z;
    int h = (colBase + wc * 64) >> 6;          // wave covers exactly one head
    if (z == 2) {
      // fused RoPE + transpose epilogue -> Vt (bh, d, n)
#pragma unroll
      for (int m = 0; m < 4; m++) {
#pragma unroll
        for (int r = 0; r < 4; r++) {
          int row = rowBase + wr * 64 + m * 16 + lg * 4 + r;
          int nrow = row & (SEQ - 1);
          int b2 = row >> 11;
          const float2* csr = cs + (size_t)nrow * 32;
          float a0 = acc[m][0][r], a1 = acc[m][1][r];
          float2 f0 = csr[lr];
          float2 f1 = csr[16 + lr];
          float o0 = a0 * f0.x - a1 * f0.y;
          float o1 = a1 * f1.x + a0 * f1.y;
          size_t vbase = ((size_t)(b2 * NHEADS + h) * 64) * SEQ + nrow;
          Vt[vbase + (size_t)lr * SEQ]        = f2b(o0);
          Vt[vbase + (size_t)(16 + lr) * SEQ] = f2b(o1);
          Vt[vbase + (size_t)(32 + lr) * SEQ] = f2b(acc[m][2][r]);
          Vt[vbase + (size_t)(48 + lr) * SEQ] = f2b(acc[m][3][r]);
        }
      }
    } else {
      // fused RoPE epilogue -> Qh / Kh (bh, n, d)
      u16* C = (z == 0) ? Qh : Kh;
      float sc = (z == 0) ? QSCALE : 1.0f;
#pragma unroll
      for (int m = 0; m < 4; m++) {
#pragma unroll
        for (int r = 0; r < 4; r++) {
          int row = rowBase + wr * 64 + m * 16 + lg * 4 + r;
          int nrow = row & (SEQ - 1);
          int b2 = row >> 11;
          const float2* csr = cs + (size_t)nrow * 32;
          float a0 = acc[m][0][r], a1 = acc[m][1][r];
          float2 f0 = csr[lr];        // d = lr
          float2 f1 = csr[16 + lr];   // d = 16+lr
          float o0 = (a0 * f0.x - a1 * f0.y) * sc;
          float o1 = (a1 * f1.x + a0 * f1.y) * sc;
          size_t base = ((size_t)(b2 * NHEADS + h) * SEQ + nrow) * 64;
          C[base + lr]      = f2b(o0);
          C[base + 16 + lr] = f2b(o1);
          C[base + 32 + lr] = f2b(acc[m][2][r] * sc);
          C[base + 48 + lr] = f2b(acc[m][3][r] * sc);
        }
      }
    }
  }
}

// ---------------- causal flash attention ----------------
// 256 threads = 4 waves; each wave owns 16 q-rows (64-row Q tile / block).
// Block pi handles 64-row q-tiles pi and 31-pi sequentially -> 33 kt-iters.
// XCD-aware remap: each XCD owns 4 bh entirely -> K/V L2-resident (2MB/XCD).
__global__ __launch_bounds__(256) void attn_kernel(
    const u16* __restrict__ Qh, const u16* __restrict__ Kh,
    const u16* __restrict__ Vtg, u16* __restrict__ Ob) {
  int id = blockIdx.x;                     // 0..511
  int xcd = id & 7, within = id >> 3;      // 64 blocks per XCD
  int bh = xcd * 4 + (within >> 4);        // 4 bh per XCD
  int pi = within & 15;                    // 0..15
  int b = bh >> 4, h = bh & 15;
  __shared__ u16 Ks[2][64 * 64];
  __shared__ u16 Vs[2][64 * 64];           // [d][kpos]
  __shared__ u16 Ps[4][16 * 64];
  int t = threadIdx.x, w = t >> 6, l = t & 63;
  int lr = l & 15, lg = l >> 4;
  char* psb = (char*)&Ps[w][0];

  const char* Kbh = (const char*)(Kh + (size_t)bh * SEQ * 64);
  const char* Vbh = (const char*)Vtg + (size_t)bh * 64 * SEQ * 2;
  const u16* Qbh = Qh + (size_t)bh * SEQ * 64;

  auto stage = [&](int buf, int kt) {
    const char* kg = Kbh + (size_t)kt * 64 * 128;   // K rows contiguous 128B
    const char* vg = Vbh + kt * 128;                // V rows stride SEQ*2
#pragma unroll
    for (int i = 0; i < 2; i++) {
      int ob = i * 4096 + t * 16;          // 256 lanes x 16B x 2 = 8KB
      int row = ob >> 7, cb = ob & 127;
      int sw = cb ^ ((row & 7) << 4);
      gload_lds16((char*)&Ks[buf][0] + ob, kg + row * 128 + sw);
      gload_lds16((char*)&Vs[buf][0] + ob, vg + row * 4096 + sw);
    }
  };

#pragma unroll 1
  for (int ph = 0; ph < 2; ++ph) {
    int qt = ph ? (31 - pi) : pi;          // 64-row q tile index
    int nkt = qt + 1;
    int qrow0 = qt * 64 + w * 16;

    s16x8 qf[2];
#pragma unroll
    for (int kk = 0; kk < 2; kk++)
      qf[kk] = *(const s16x8*)(Qbh + (size_t)(qrow0 + lr) * 64 + kk * 32 + lg * 8);

    f32x4 o[4];
#pragma unroll
    for (int n = 0; n < 4; n++) o[n] = (f32x4){0.f, 0.f, 0.f, 0.f};
    float mrun[4], lsum[4];
#pragma unroll
    for (int r = 0; r < 4; r++) { mrun[r] = -3.0e38f; lsum[r] = 0.f; }

    __syncthreads();                       // prior phase LDS reads fully done
    stage(0, 0);
    for (int kt = 0; kt < nkt; ++kt) {
      int cur = kt & 1;
      __syncthreads();                     // drains vmcnt: buf cur staged
      if (kt + 1 < nkt) stage(cur ^ 1, kt + 1);
      const char* kb = (const char*)&Ks[cur][0];
      const char* vb = (const char*)&Vs[cur][0];

      // S = Q K^T (scale+log2e folded into Q)
      f32x4 s[4];
#pragma unroll
      for (int n = 0; n < 4; n++) s[n] = (f32x4){0.f, 0.f, 0.f, 0.f};
      __builtin_amdgcn_s_setprio(1);
#pragma unroll
      for (int n = 0; n < 4; n++)
#pragma unroll
        for (int kk = 0; kk < 2; kk++) {
          int R = n * 16 + lr;
          s16x8 bk = *(const s16x8*)(kb + R * 128 + ((kk * 64 + lg * 16) ^ ((R & 7) << 4)));
          s[n] = __builtin_amdgcn_mfma_f32_16x16x32_bf16(qf[kk], bk, s[n], 0, 0, 0);
        }
      __builtin_amdgcn_s_setprio(0);

      if (kt == nkt - 1) {                 // causal mask (diagonal tile)
#pragma unroll
        for (int n = 0; n < 4; n++) {
          int colg = kt * 64 + n * 16 + lr;
#pragma unroll
          for (int r = 0; r < 4; r++) {
            int rowg = qt * 64 + w * 16 + lg * 4 + r;
            if (colg > rowg) s[n][r] = -3.0e38f;
          }
        }
      }

      // online softmax (exp2 domain), defer-max with per-lane trigger (T13)
      float tl[4];
#pragma unroll
      for (int r = 0; r < 4; r++)
        tl[r] = fmaxf(fmaxf(s[0][r], s[1][r]), fmaxf(s[2][r], s[3][r]));
      float need = fmaxf(fmaxf(tl[0] - mrun[0], tl[1] - mrun[1]),
                         fmaxf(tl[2] - mrun[2], tl[3] - mrun[3]));
      if (!__all(need <= DEFER_THR)) {     // rare: full reduce + rescale
        float tm[4];
#pragma unroll
        for (int r = 0; r < 4; r++) tm[r] = tl[r];
#pragma unroll
        for (int off = 1; off < 16; off <<= 1)
#pragma unroll
          for (int r = 0; r < 4; r++) tm[r] = fmaxf(tm[r], __shfl_xor(tm[r], off, 64));
        float alpha[4];
#pragma unroll
        for (int r = 0; r < 4; r++) {
          float mn = fmaxf(mrun[r], tm[r]);
          alpha[r] = exp2f(mrun[r] - mn);
          mrun[r] = mn;
          lsum[r] *= alpha[r];
        }
#pragma unroll
        for (int n = 0; n < 4; n++)
#pragma unroll
          for (int r = 0; r < 4; r++) o[n][r] *= alpha[r];
      }
#pragma unroll
      for (int n = 0; n < 4; n++) {
#pragma unroll
        for (int r = 0; r < 4; r++) {
          float p = exp2f(s[n][r] - mrun[r]);
          lsum[r] += p;
          int prow = lg * 4 + r;
          *(u16*)(psb + prow * 128 + (((n * 16 + lr) * 2) ^ ((prow & 7) << 4))) = f2b_fast(p);
        }
      }
      // P is per-wave only: no barrier needed (compiler inserts lgkm waits)

      s16x8 pa[2];
#pragma unroll
      for (int kk = 0; kk < 2; kk++)
        pa[kk] = *(const s16x8*)(psb + lr * 128 + ((kk * 64 + lg * 16) ^ ((lr & 7) << 4)));
      __builtin_amdgcn_s_setprio(1);
#pragma unroll
      for (int n = 0; n < 4; n++)
#pragma unroll
        for (int kk = 0; kk < 2; kk++) {
          int R = n * 16 + lr;
          s16x8 vv = *(const s16x8*)(vb + R * 128 + ((kk * 64 + lg * 16) ^ ((R & 7) << 4)));
          o[n] = __builtin_amdgcn_mfma_f32_16x16x32_bf16(pa[kk], vv, o[n], 0, 0, 0);
        }
      __builtin_amdgcn_s_setprio(0);
    }

    // finalize this q-tile
#pragma unroll
    for (int off = 1; off < 16; off <<= 1)
#pragma unroll
      for (int r = 0; r < 4; r++) lsum[r] += __shfl_xor(lsum[r], off, 64);
    float inv[4];
#pragma unroll
    for (int r = 0; r < 4; r++) inv[r] = 1.0f / lsum[r];
#pragma unroll
    for (int n = 0; n < 4; n++)
#pragma unroll
      for (int r = 0; r < 4; r++) {
        int rowg = qt * 64 + w * 16 + lg * 4 + r;
        int col = h * 64 + n * 16 + lr;
        Ob[((size_t)b * SEQ + rowg) * DIM + col] = f2b(o[n][r] * inv[r]);
      }
  }
}

// ---------------- launch ----------------
extern "C" void kernel_launch(void* const* d_in, const int* in_sizes, int n_in,
                              void* d_out, int out_size, void* d_ws, size_t ws_size,
                              hipStream_t stream) {
  (void)in_sizes; (void)n_in; (void)out_size; (void)ws_size;
  const float* x = (const float*)d_in[0];
  const float* rot = (const float*)d_in[1];
  const float* Wq = (const float*)d_in[2];
  const float* Wk = (const float*)d_in[3];
  const float* Wv = (const float*)d_in[4];
  const float* Wo = (const float*)d_in[5];

  char* ws = (char*)d_ws;
  u16* xb    = (u16*)(ws);                         // 8 MB
  u16* WtAll = (u16*)(ws + (8ll << 20));           // 8 MB
  u16* Qh    = (u16*)(ws + (16ll << 20));          // 8 MB
  u16* Kh    = (u16*)(ws + (24ll << 20));          // 8 MB
  u16* Vt    = (u16*)(ws + (32ll << 20));          // 8 MB
  u16* Ob    = (u16*)(ws + (40ll << 20));          // 8 MB
  float2* cs = (float2*)(ws + (48ll << 20));       // 0.5 MB

  prep_kernel<<<8448, 256, 0, stream>>>(x, Wq, Wk, Wv, Wo, rot, xb, WtAll, cs);
  gemm128<0><<<dim3(32, 8, 3), 256, 0, stream>>>(xb, WtAll, nullptr, cs, Qh, Kh, Vt);
  attn_kernel<<<512, 256, 0, stream>>>(Qh, Kh, Vt, Ob);
  gemm128<1><<<dim3(32, 8, 1), 256, 0, stream>>>(Ob, WtAll + 3ll * DIM * DIM, d_out,
                                                 nullptr, nullptr, nullptr, nullptr);
}

// Round 5
// 199.467 us; speedup vs baseline: 1.5101x; 1.0655x over previous
//
#include <hip/hip_runtime.h>
#include <hip/hip_bf16.h>
#include <stdint.h>

#define BATCH 2
#define SEQ 2048
#define NHEADS 16
#define DIM 1024
#define MTOT 4096            // BATCH*SEQ
#define LOG2E 1.4426950408889634f
#define QSCALE (0.125f * LOG2E)   // d^-0.5 * log2(e), folded into Q
#define DEFER_THR 11.54f          // 8 * log2(e): defer-max threshold (exp2 domain)

typedef __attribute__((ext_vector_type(8))) short s16x8;   // 8 bf16
typedef __attribute__((ext_vector_type(4))) float f32x4;
typedef unsigned short u16;

__device__ __forceinline__ u16 f2b(float f) {       // RNE (epilogues)
  union { float f; uint32_t u; } v; v.f = f;
  uint32_t r = v.u + 0x7FFFu + ((v.u >> 16) & 1u);
  return (u16)(r >> 16);
}
__device__ __forceinline__ u16 f2b_fast(float f) {  // round-nearest-up (P path)
  union { float f; uint32_t u; } v; v.f = f;
  return (u16)((v.u + 0x8000u) >> 16);
}
__device__ __forceinline__ float b2f(u16 h) {
  union { uint32_t u; float f; } v; v.u = ((uint32_t)h) << 16;
  return v.f;
}

// async global->LDS, 16B per lane. LDS dest must be uniform-base + lane*16.
__device__ __forceinline__ void gload_lds16(void* lds, const void* g) {
  __builtin_amdgcn_global_load_lds(
      (const __attribute__((address_space(1))) unsigned int*)g,
      (__attribute__((address_space(3))) unsigned int*)lds, 16, 0, 0);
}

// ---------------- fused prep: cast x, transpose weights, cos/sin table ----
__global__ __launch_bounds__(256) void prep_kernel(
    const float* __restrict__ x, const float* __restrict__ Wq,
    const float* __restrict__ Wk, const float* __restrict__ Wv,
    const float* __restrict__ Wo, const float* __restrict__ rot,
    u16* __restrict__ xb, u16* __restrict__ WtAll, float2* __restrict__ cs) {
  __shared__ float tile[32][33];
  int bid = blockIdx.x, t = threadIdx.x;
  if (bid < 4096) {                          // cast x -> bf16
    int i = (bid * 256 + t) * 4;
    float4 v = *(const float4*)(x + i);
    ushort4 o;
    o.x = f2b(v.x); o.y = f2b(v.y); o.z = f2b(v.z); o.w = f2b(v.w);
    *(ushort4*)(xb + i) = o;
  } else if (bid < 8192) {                   // W -> W^T bf16
    int bb = bid - 4096;
    int z = bb >> 10, xB = bb & 31, yB = (bb >> 5) & 31;
    const float* W = (z == 0) ? Wq : (z == 1) ? Wk : (z == 2) ? Wv : Wo;
    u16* Wt = WtAll + (size_t)z * DIM * DIM;
    int k0 = xB * 32, n0 = yB * 32;
    int tx = t & 31, ty = t >> 5;
#pragma unroll
    for (int i = 0; i < 4; i++) {
      int r = ty + i * 8;
      tile[r][tx] = W[(size_t)(k0 + r) * DIM + n0 + tx];
    }
    __syncthreads();
#pragma unroll
    for (int i = 0; i < 4; i++) {
      int r = ty + i * 8;
      Wt[(size_t)(n0 + r) * DIM + k0 + tx] = f2b(tile[tx][r]);
    }
  } else {                                   // cos/sin table
    int i = (bid - 8192) * 256 + t;          // SEQ*32 = 65536
    float f = rot[i];
    float s, c;
    __sincosf(f, &s, &c);
    cs[i] = make_float2(c, s);
  }
}

// ---------------- fused QKV GEMM: 256x256 tile, BK=64, 8-phase pipeline ----
// C(4096 x 3072) = xb(4096 x 1024) x WtAll(3072 x 1024)^T, rope epilogues.
// 512 threads = 8 waves (2M x 4N); per-wave output 128x64 (one head's cols).
// LDS: 2 bufs x 4 half-tiles (A-K0, A-K1, B-K0, B-K1) x 16KB = 128KB.
// Counted vmcnt(6) at K-tile boundaries only (3 half-tiles in flight).
#define NKT 16    // K-tiles: 1024 / 64
__global__ __launch_bounds__(512, 2) void qkv8_kernel(
    const u16* __restrict__ A, const u16* __restrict__ Bt,
    const float2* __restrict__ cs, u16* __restrict__ Qh,
    u16* __restrict__ Kh, u16* __restrict__ Vt) {
  __shared__ u16 lds[2][4][8192];   // [buf][0=A-K0,1=A-K1,2=B-K0,3=B-K1][256*32]
  const int t = threadIdx.x;
  const int w = t >> 6, l = t & 63;
  const int wr = w >> 2, wc = w & 3;          // 2 x 4 wave grid
  const int lr = l & 15, lg = l >> 4;
  const int rowBase = blockIdx.x * 256;
  const int colBase = blockIdx.y * 256;
  const char* Ab = (const char*)(A + (size_t)rowBase * DIM);
  const char* Bb = (const char*)(Bt + (size_t)colBase * DIM);
  const int t16 = t * 16;
  const int swz = ((lr >> 1) & 3) << 4;

  f32x4 acc[8][4];
#pragma unroll
  for (int m = 0; m < 8; m++)
#pragma unroll
    for (int n = 0; n < 4; n++) acc[m][n] = (f32x4){0.f, 0.f, 0.f, 0.f};

  // stage one 16KB half-tile. kind: 0=A-K0, 1=A-K1, 2=B-K0, 3=B-K1
  auto stageH = [&](int buf, int kind, int kt) {
    const char* gb = (kind >= 2) ? Bb : Ab;
    int khalf = kind & 1;
    char* ldst = (char*)&lds[buf][kind][0];
#pragma unroll
    for (int i = 0; i < 2; i++) {
      int ob = t16 + i * 8192;               // 512 thr x 16B x 2 = 16KB
      int row = ob >> 6, cb = ob & 63;       // 256 rows x 64B
      gload_lds16(ldst + ob,
                  gb + (size_t)row * (DIM * 2) + kt * 128 + khalf * 64 +
                      (cb ^ (((row >> 1) & 3) << 4)));
    }
  };
  auto rdA = [&](int cur, int m, int kk) -> s16x8 {
    int R = wr * 128 + m * 16 + lr;
    return *(const s16x8*)((const char*)&lds[cur][kk][0] + R * 64 + ((lg * 16) ^ swz));
  };
  auto rdB = [&](int cur, int n, int kk) -> s16x8 {
    int R = wc * 64 + n * 16 + lr;
    return *(const s16x8*)((const char*)&lds[cur][2 + kk][0] + R * 64 + ((lg * 16) ^ swz));
  };

  // prologue: 7 halves in steady-state stream order
  stageH(0, 0, 0); stageH(0, 2, 0); stageH(0, 1, 0); stageH(0, 3, 0);
  stageH(1, 2, 1); stageH(1, 0, 1); stageH(1, 3, 1);

  for (int kt = 0; kt < NKT; ++kt) {
    const int cur = kt & 1, nxt = cur ^ 1;
    // tile boundary: all 4 halves of tile kt guaranteed landed (3 newer fly)
    if (kt >= NKT - 2) { asm volatile("s_waitcnt vmcnt(0)" ::: "memory"); }
    else               { asm volatile("s_waitcnt vmcnt(6)" ::: "memory"); }
    __builtin_amdgcn_s_barrier();
    __builtin_amdgcn_sched_barrier(0);

    s16x8 af[4], bf[4];
    // ---- phase 0: kk0, m0-3 (+ B kk0); stage A-K1(kt+1)
#pragma unroll
    for (int i = 0; i < 4; i++) { af[i] = rdA(cur, i, 0); bf[i] = rdB(cur, i, 0); }
    if (kt + 1 < NKT) stageH(nxt, 1, kt + 1);
    __builtin_amdgcn_s_barrier();
    __builtin_amdgcn_sched_barrier(0);
    __builtin_amdgcn_s_setprio(1);
#pragma unroll
    for (int m = 0; m < 4; m++)
#pragma unroll
      for (int n = 0; n < 4; n++)
        acc[m][n] = __builtin_amdgcn_mfma_f32_16x16x32_bf16(af[m], bf[n], acc[m][n], 0, 0, 0);
    __builtin_amdgcn_s_setprio(0);
    __builtin_amdgcn_s_barrier();
    __builtin_amdgcn_sched_barrier(0);
    // ---- phase 1: kk0, m4-7; stage B-K0(kt+2)
#pragma unroll
    for (int i = 0; i < 4; i++) af[i] = rdA(cur, 4 + i, 0);
    if (kt + 2 < NKT) stageH(cur, 2, kt + 2);
    __builtin_amdgcn_s_barrier();
    __builtin_amdgcn_sched_barrier(0);
    __builtin_amdgcn_s_setprio(1);
#pragma unroll
    for (int m = 0; m < 4; m++)
#pragma unroll
      for (int n = 0; n < 4; n++)
        acc[4 + m][n] = __builtin_amdgcn_mfma_f32_16x16x32_bf16(af[m], bf[n], acc[4 + m][n], 0, 0, 0);
    __builtin_amdgcn_s_setprio(0);
    __builtin_amdgcn_s_barrier();
    __builtin_amdgcn_sched_barrier(0);
    // ---- phase 2: kk1, m0-3 (+ B kk1); stage A-K0(kt+2)
#pragma unroll
    for (int i = 0; i < 4; i++) { af[i] = rdA(cur, i, 1); bf[i] = rdB(cur, i, 1); }
    if (kt + 2 < NKT) stageH(cur, 0, kt + 2);
    __builtin_amdgcn_s_barrier();
    __builtin_amdgcn_sched_barrier(0);
    __builtin_amdgcn_s_setprio(1);
#pragma unroll
    for (int m = 0; m < 4; m++)
#pragma unroll
      for (int n = 0; n < 4; n++)
        acc[m][n] = __builtin_amdgcn_mfma_f32_16x16x32_bf16(af[m], bf[n], acc[m][n], 0, 0, 0);
    __builtin_amdgcn_s_setprio(0);
    __builtin_amdgcn_s_barrier();
    __builtin_amdgcn_sched_barrier(0);
    // ---- phase 3: kk1, m4-7; stage B-K1(kt+2)
#pragma unroll
    for (int i = 0; i < 4; i++) af[i] = rdA(cur, 4 + i, 1);
    if (kt + 2 < NKT) stageH(cur, 3, kt + 2);
    __builtin_amdgcn_s_barrier();
    __builtin_amdgcn_sched_barrier(0);
    __builtin_amdgcn_s_setprio(1);
#pragma unroll
    for (int m = 0; m < 4; m++)
#pragma unroll
      for (int n = 0; n < 4; n++)
        acc[4 + m][n] = __builtin_amdgcn_mfma_f32_16x16x32_bf16(af[m], bf[n], acc[4 + m][n], 0, 0, 0);
    __builtin_amdgcn_s_setprio(0);
    __builtin_amdgcn_s_barrier();
    __builtin_amdgcn_sched_barrier(0);
  }

  // ---- rope epilogues (per wave: one head's 64 cols) ----
  int cg = colBase + wc * 64;
  int z = cg >> 10;
  int h = (cg >> 6) & (NHEADS - 1);
  if (z == 2) {
    // rope + transpose -> Vt (bh, d, n)
#pragma unroll
    for (int m = 0; m < 8; m++) {
#pragma unroll
      for (int r = 0; r < 4; r++) {
        int row = rowBase + wr * 128 + m * 16 + lg * 4 + r;
        int nrow = row & (SEQ - 1);
        int b2 = row >> 11;
        const float2* csr = cs + (size_t)nrow * 32;
        float a0 = acc[m][0][r], a1 = acc[m][1][r];
        float2 f0 = csr[lr];
        float2 f1 = csr[16 + lr];
        float o0 = a0 * f0.x - a1 * f0.y;
        float o1 = a1 * f1.x + a0 * f1.y;
        size_t vbase = ((size_t)(b2 * NHEADS + h) * 64) * SEQ + nrow;
        Vt[vbase + (size_t)lr * SEQ]        = f2b(o0);
        Vt[vbase + (size_t)(16 + lr) * SEQ] = f2b(o1);
        Vt[vbase + (size_t)(32 + lr) * SEQ] = f2b(acc[m][2][r]);
        Vt[vbase + (size_t)(48 + lr) * SEQ] = f2b(acc[m][3][r]);
      }
    }
  } else {
    // rope -> Qh / Kh (bh, n, d)
    u16* C = (z == 0) ? Qh : Kh;
    float sc = (z == 0) ? QSCALE : 1.0f;
#pragma unroll
    for (int m = 0; m < 8; m++) {
#pragma unroll
      for (int r = 0; r < 4; r++) {
        int row = rowBase + wr * 128 + m * 16 + lg * 4 + r;
        int nrow = row & (SEQ - 1);
        int b2 = row >> 11;
        const float2* csr = cs + (size_t)nrow * 32;
        float a0 = acc[m][0][r], a1 = acc[m][1][r];
        float2 f0 = csr[lr];        // d = lr
        float2 f1 = csr[16 + lr];   // d = 16+lr
        float o0 = (a0 * f0.x - a1 * f0.y) * sc;
        float o1 = (a1 * f1.x + a0 * f1.y) * sc;
        size_t base = ((size_t)(b2 * NHEADS + h) * SEQ + nrow) * 64;
        C[base + lr]      = f2b(o0);
        C[base + 16 + lr] = f2b(o1);
        C[base + 32 + lr] = f2b(acc[m][2][r] * sc);
        C[base + 48 + lr] = f2b(acc[m][3][r] * sc);
      }
    }
  }
}

// ---------------- out-projection GEMM (128x128 tile, 2-phase dbuf) --------
__global__ __launch_bounds__(256) void gemm_out(
    const u16* __restrict__ A, const u16* __restrict__ Bt,
    float* __restrict__ C) {
  __shared__ u16 Asm[2][128 * 32];
  __shared__ u16 Bsm[2][128 * 32];
  int t = threadIdx.x;
  int w = t >> 6, l = t & 63;
  int wr = w >> 1, wc = w & 1;
  int lr = l & 15, lg = l >> 4;
  int rowBase = blockIdx.x * 128;
  int colBase = blockIdx.y * 128;
  const char* Ab = (const char*)(A + (size_t)rowBase * DIM);
  const char* Bb = (const char*)(Bt + (size_t)colBase * DIM);

  f32x4 acc[4][4];
#pragma unroll
  for (int m = 0; m < 4; m++)
#pragma unroll
    for (int n = 0; n < 4; n++) acc[m][n] = (f32x4){0.f, 0.f, 0.f, 0.f};

  auto stage = [&](int buf, int kt) {
#pragma unroll
    for (int i = 0; i < 2; i++) {
      int ob = t * 16 + i * 4096;
      int row = ob >> 6, cb = ob & 63;
      int src = row * (DIM * 2) + kt * 64 + (cb ^ (((row >> 1) & 3) << 4));
      gload_lds16((char*)&Asm[buf][0] + ob, Ab + src);
      gload_lds16((char*)&Bsm[buf][0] + ob, Bb + src);
    }
  };

  stage(0, 0);
  for (int kt = 0; kt < DIM / 32; ++kt) {
    int cur = kt & 1;
    __syncthreads();
    if (kt + 1 < DIM / 32) stage(cur ^ 1, kt + 1);
    const char* ab = (const char*)&Asm[cur][0];
    const char* bb = (const char*)&Bsm[cur][0];
    s16x8 af[4], bf[4];
#pragma unroll
    for (int m = 0; m < 4; m++) {
      int R = wr * 64 + m * 16 + lr;
      af[m] = *(const s16x8*)(ab + R * 64 + ((lg * 16) ^ (((R >> 1) & 3) << 4)));
    }
#pragma unroll
    for (int n = 0; n < 4; n++) {
      int R = wc * 64 + n * 16 + lr;
      bf[n] = *(const s16x8*)(bb + R * 64 + ((lg * 16) ^ (((R >> 1) & 3) << 4)));
    }
    __builtin_amdgcn_s_setprio(1);
#pragma unroll
    for (int m = 0; m < 4; m++)
#pragma unroll
      for (int n = 0; n < 4; n++)
        acc[m][n] = __builtin_amdgcn_mfma_f32_16x16x32_bf16(af[m], bf[n], acc[m][n], 0, 0, 0);
    __builtin_amdgcn_s_setprio(0);
  }

#pragma unroll
  for (int m = 0; m < 4; m++)
#pragma unroll
    for (int n = 0; n < 4; n++) {
      int row = rowBase + wr * 64 + m * 16 + lg * 4;
      int col = colBase + wc * 64 + n * 16 + lr;
#pragma unroll
      for (int r = 0; r < 4; r++)
        C[(size_t)(row + r) * DIM + col] = acc[m][n][r];
    }
}

// ---------------- causal flash attention ----------------
// 256 threads = 4 waves; each wave owns 16 q-rows (64-row Q tile / block).
// Block pi handles 64-row q-tiles pi and 31-pi sequentially -> 33 kt-iters.
// XCD-aware remap: each XCD owns 4 bh entirely -> K/V L2-resident (2MB/XCD).
__global__ __launch_bounds__(256) void attn_kernel(
    const u16* __restrict__ Qh, const u16* __restrict__ Kh,
    const u16* __restrict__ Vtg, u16* __restrict__ Ob) {
  int id = blockIdx.x;                     // 0..511
  int xcd = id & 7, within = id >> 3;      // 64 blocks per XCD
  int bh = xcd * 4 + (within >> 4);        // 4 bh per XCD
  int pi = within & 15;                    // 0..15
  int b = bh >> 4, h = bh & 15;
  __shared__ u16 Ks[2][64 * 64];
  __shared__ u16 Vs[2][64 * 64];           // [d][kpos]
  __shared__ u16 Ps[4][16 * 64];
  int t = threadIdx.x, w = t >> 6, l = t & 63;
  int lr = l & 15, lg = l >> 4;
  char* psb = (char*)&Ps[w][0];

  const char* Kbh = (const char*)(Kh + (size_t)bh * SEQ * 64);
  const char* Vbh = (const char*)Vtg + (size_t)bh * 64 * SEQ * 2;
  const u16* Qbh = Qh + (size_t)bh * SEQ * 64;

  auto stage = [&](int buf, int kt) {
    const char* kg = Kbh + (size_t)kt * 64 * 128;   // K rows contiguous 128B
    const char* vg = Vbh + kt * 128;                // V rows stride SEQ*2
#pragma unroll
    for (int i = 0; i < 2; i++) {
      int ob = i * 4096 + t * 16;          // 256 lanes x 16B x 2 = 8KB
      int row = ob >> 7, cb = ob & 127;
      int sw = cb ^ ((row & 7) << 4);
      gload_lds16((char*)&Ks[buf][0] + ob, kg + row * 128 + sw);
      gload_lds16((char*)&Vs[buf][0] + ob, vg + row * 4096 + sw);
    }
  };

#pragma unroll 1
  for (int ph = 0; ph < 2; ++ph) {
    int qt = ph ? (31 - pi) : pi;          // 64-row q tile index
    int nkt = qt + 1;
    int qrow0 = qt * 64 + w * 16;

    s16x8 qf[2];
#pragma unroll
    for (int kk = 0; kk < 2; kk++)
      qf[kk] = *(const s16x8*)(Qbh + (size_t)(qrow0 + lr) * 64 + kk * 32 + lg * 8);

    f32x4 o[4];
#pragma unroll
    for (int n = 0; n < 4; n++) o[n] = (f32x4){0.f, 0.f, 0.f, 0.f};
    float mrun[4], lsum[4];
#pragma unroll
    for (int r = 0; r < 4; r++) { mrun[r] = -3.0e38f; lsum[r] = 0.f; }

    __syncthreads();                       // prior phase LDS reads fully done
    stage(0, 0);
    for (int kt = 0; kt < nkt; ++kt) {
      int cur = kt & 1;
      __syncthreads();                     // drains vmcnt: buf cur staged
      if (kt + 1 < nkt) stage(cur ^ 1, kt + 1);
      const char* kb = (const char*)&Ks[cur][0];
      const char* vb = (const char*)&Vs[cur][0];

      // S = Q K^T (scale+log2e folded into Q)
      f32x4 s[4];
#pragma unroll
      for (int n = 0; n < 4; n++) s[n] = (f32x4){0.f, 0.f, 0.f, 0.f};
      __builtin_amdgcn_s_setprio(1);
#pragma unroll
      for (int n = 0; n < 4; n++)
#pragma unroll
        for (int kk = 0; kk < 2; kk++) {
          int R = n * 16 + lr;
          s16x8 bk = *(const s16x8*)(kb + R * 128 + ((kk * 64 + lg * 16) ^ ((R & 7) << 4)));
          s[n] = __builtin_amdgcn_mfma_f32_16x16x32_bf16(qf[kk], bk, s[n], 0, 0, 0);
        }
      __builtin_amdgcn_s_setprio(0);

      if (kt == nkt - 1) {                 // causal mask (diagonal tile)
#pragma unroll
        for (int n = 0; n < 4; n++) {
          int colg = kt * 64 + n * 16 + lr;
#pragma unroll
          for (int r = 0; r < 4; r++) {
            int rowg = qt * 64 + w * 16 + lg * 4 + r;
            if (colg > rowg) s[n][r] = -3.0e38f;
          }
        }
      }

      // online softmax (exp2 domain), defer-max with per-lane trigger (T13)
      float tl[4];
#pragma unroll
      for (int r = 0; r < 4; r++)
        tl[r] = fmaxf(fmaxf(s[0][r], s[1][r]), fmaxf(s[2][r], s[3][r]));
      float need = fmaxf(fmaxf(tl[0] - mrun[0], tl[1] - mrun[1]),
                         fmaxf(tl[2] - mrun[2], tl[3] - mrun[3]));
      if (!__all(need <= DEFER_THR)) {     // rare: full reduce + rescale
        float tm[4];
#pragma unroll
        for (int r = 0; r < 4; r++) tm[r] = tl[r];
#pragma unroll
        for (int off = 1; off < 16; off <<= 1)
#pragma unroll
          for (int r = 0; r < 4; r++) tm[r] = fmaxf(tm[r], __shfl_xor(tm[r], off, 64));
        float alpha[4];
#pragma unroll
        for (int r = 0; r < 4; r++) {
          float mn = fmaxf(mrun[r], tm[r]);
          alpha[r] = exp2f(mrun[r] - mn);
          mrun[r] = mn;
          lsum[r] *= alpha[r];
        }
#pragma unroll
        for (int n = 0; n < 4; n++)
#pragma unroll
          for (int r = 0; r < 4; r++) o[n][r] *= alpha[r];
      }
#pragma unroll
      for (int n = 0; n < 4; n++) {
#pragma unroll
        for (int r = 0; r < 4; r++) {
          float p = exp2f(s[n][r] - mrun[r]);
          lsum[r] += p;
          int prow = lg * 4 + r;
          *(u16*)(psb + prow * 128 + (((n * 16 + lr) * 2) ^ ((prow & 7) << 4))) = f2b_fast(p);
        }
      }
      // P is per-wave only: no barrier needed (compiler inserts lgkm waits)

      s16x8 pa[2];
#pragma unroll
      for (int kk = 0; kk < 2; kk++)
        pa[kk] = *(const s16x8*)(psb + lr * 128 + ((kk * 64 + lg * 16) ^ ((lr & 7) << 4)));
      __builtin_amdgcn_s_setprio(1);
#pragma unroll
      for (int n = 0; n < 4; n++)
#pragma unroll
        for (int kk = 0; kk < 2; kk++) {
          int R = n * 16 + lr;
          s16x8 vv = *(const s16x8*)(vb + R * 128 + ((kk * 64 + lg * 16) ^ ((R & 7) << 4)));
          o[n] = __builtin_amdgcn_mfma_f32_16x16x32_bf16(pa[kk], vv, o[n], 0, 0, 0);
        }
      __builtin_amdgcn_s_setprio(0);
    }

    // finalize this q-tile
#pragma unroll
    for (int off = 1; off < 16; off <<= 1)
#pragma unroll
      for (int r = 0; r < 4; r++) lsum[r] += __shfl_xor(lsum[r], off, 64);
    float inv[4];
#pragma unroll
    for (int r = 0; r < 4; r++) inv[r] = 1.0f / lsum[r];
#pragma unroll
    for (int n = 0; n < 4; n++)
#pragma unroll
      for (int r = 0; r < 4; r++) {
        int rowg = qt * 64 + w * 16 + lg * 4 + r;
        int col = h * 64 + n * 16 + lr;
        Ob[((size_t)b * SEQ + rowg) * DIM + col] = f2b(o[n][r] * inv[r]);
      }
  }
}

// ---------------- launch ----------------
extern "C" void kernel_launch(void* const* d_in, const int* in_sizes, int n_in,
                              void* d_out, int out_size, void* d_ws, size_t ws_size,
                              hipStream_t stream) {
  (void)in_sizes; (void)n_in; (void)out_size; (void)ws_size;
  const float* x = (const float*)d_in[0];
  const float* rot = (const float*)d_in[1];
  const float* Wq = (const float*)d_in[2];
  const float* Wk = (const float*)d_in[3];
  const float* Wv = (const float*)d_in[4];
  const float* Wo = (const float*)d_in[5];

  char* ws = (char*)d_ws;
  u16* xb    = (u16*)(ws);                         // 8 MB
  u16* WtAll = (u16*)(ws + (8ll << 20));           // 8 MB
  u16* Qh    = (u16*)(ws + (16ll << 20));          // 8 MB
  u16* Kh    = (u16*)(ws + (24ll << 20));          // 8 MB
  u16* Vt    = (u16*)(ws + (32ll << 20));          // 8 MB
  u16* Ob    = (u16*)(ws + (40ll << 20));          // 8 MB
  float2* cs = (float2*)(ws + (48ll << 20));       // 0.5 MB

  prep_kernel<<<8448, 256, 0, stream>>>(x, Wq, Wk, Wv, Wo, rot, xb, WtAll, cs);
  qkv8_kernel<<<dim3(16, 12), 512, 0, stream>>>(xb, WtAll, cs, Qh, Kh, Vt);
  attn_kernel<<<512, 256, 0, stream>>>(Qh, Kh, Vt, Ob);
  gemm_out<<<dim3(32, 8), 256, 0, stream>>>(Ob, WtAll + 3ll * DIM * DIM, (float*)d_out);
}